// Round 1
// baseline (426.921 us; speedup 1.0000x reference)
//
#include <hip/hip_runtime.h>
#include <stdint.h>

// HMM trajectory-net forward:  -logsumexp over an 8191-step 64-state HMM scan.
// Pipeline:
//   conv_*      : fp32 -> bf16 repacks (s_i row-major; W_action/W_small transposed to [col][k])
//   small_gemm  : start/stop logits via MFMA, fused softmax/sigmoid epilogue -> ps, pb, pc
//   act_gemm    : action logits via MFMA, fused row-logsumexp + action-select -> pe
//   chunk_kernel: 128 chunks x 64 steps; per-chunk 64x64 transfer matrix in registers
//                 (rank-1 + diagonal update per step, normal space + log rescale)
//   combine     : sequential 128 mat-vecs + final reduction -> scalar output

typedef short bf16x8 __attribute__((ext_vector_type(8)));
typedef float f32x4  __attribute__((ext_vector_type(4)));
typedef unsigned short u16;

#define T_LEN 8192
#define SDIM  256

// ---- workspace layout (bytes) ----
#define WS_SBF    0              // 8256*256 bf16 (padded rows zeroed)
#define WS_WAT    4227072        // 4096*256 bf16  [b*64+n][s]
#define WS_WSMT   6324224        // 192*256 bf16   [col][s]  (0..63 start, 64..127 stop0, 128..191 stop1)
#define WS_PE     6422528        // 8192*64 f32
#define WS_PS     8519680        // 8193*64 f32
#define WS_PB     10617088       // 8193*64 f32
#define WS_PC     12714496       // 8193*64 f32
#define WS_MOUT   14811904       // 128*4096 f32  [chunk][k][j]  (column-major chunk matrices)
#define WS_LSC    16909056       // 128 f32

__device__ inline u16 f2bf(float f) {
  union { float f; uint32_t u; } v; v.f = f;
  uint32_t u = v.u;
  return (u16)((u + 0x7fffu + ((u >> 16) & 1u)) >> 16);
}

// ---------------- converts ----------------
__global__ void conv_s(const float* __restrict__ s_i, u16* __restrict__ s_bf) {
  int idx = blockIdx.x * 256 + threadIdx.x;        // 8256*256 total
  int t = idx >> 8;
  float v = (t < T_LEN + 1) ? s_i[idx] : 0.f;
  s_bf[idx] = f2bf(v);
}

__global__ void conv_wa(const float* __restrict__ Wa, u16* __restrict__ wa_t) {
  int idx = blockIdx.x * 256 + threadIdx.x;        // 256*4096
  int s = idx >> 12, bn = idx & 4095;
  wa_t[bn * 256 + s] = f2bf(Wa[idx]);
}

__global__ void conv_wsm(const float* __restrict__ Wstop, const float* __restrict__ Wstart,
                         u16* __restrict__ wsm_t) {
  int idx = blockIdx.x * 256 + threadIdx.x;        // 192*256
  int col = idx >> 8, s = idx & 255;
  float v;
  if (col < 64)       v = Wstart[s * 64 + col];
  else if (col < 128) v = Wstop[s * 128 + (col - 64) * 2 + 0];
  else                v = Wstop[s * 128 + (col - 128) * 2 + 1];
  wsm_t[col * 256 + s] = f2bf(v);
}

// ---------------- action GEMM + fused emit ----------------
// grid: (64 b, 128 t-tiles of 64), block 256 (4 waves x 16 rows)
__global__ __launch_bounds__(256) void act_gemm(
    const u16* __restrict__ s_bf, const u16* __restrict__ wa_t,
    const int* __restrict__ actions, float* __restrict__ pe) {
  __shared__ uint4 ldsA[64 * 32];   // 64 rows x 256 k bf16, xor-swizzled
  __shared__ uint4 ldsB[64 * 32];
  const int b  = blockIdx.x;
  const int t0 = blockIdx.y * 64;
  const int tid = threadIdx.x;

  for (int i = tid; i < 64 * 32; i += 256) {
    int row = i >> 5, u = i & 31;
    ldsA[(row * 32 + u) ^ (row & 7)] =
        *(const uint4*)(s_bf + (size_t)(t0 + row) * 256 + u * 8);
    ldsB[(row * 32 + u) ^ (row & 7)] =
        *(const uint4*)(wa_t + (size_t)(b * 64 + row) * 256 + u * 8);
  }
  __syncthreads();

  const int lane = tid & 63, w = tid >> 6;
  const int g = lane >> 4, c = lane & 15;
  f32x4 acc[4];
#pragma unroll
  for (int i = 0; i < 4; ++i) acc[i] = (f32x4){0.f, 0.f, 0.f, 0.f};

#pragma unroll
  for (int kk = 0; kk < 8; ++kk) {
    int u = kk * 4 + g;
    int arow = w * 16 + c;
    bf16x8 af = *(const bf16x8*)&ldsA[(arow * 32 + u) ^ (arow & 7)];
#pragma unroll
    for (int cf = 0; cf < 4; ++cf) {
      int brow = cf * 16 + c;
      bf16x8 bfr = *(const bf16x8*)&ldsB[(brow * 32 + u) ^ (brow & 7)];
      acc[cf] = __builtin_amdgcn_mfma_f32_16x16x32_bf16(af, bfr, acc[cf], 0, 0, 0);
    }
  }

  // epilogue: rows w*16 + g*4 + q ; cols cf*16 + c
#pragma unroll
  for (int q = 0; q < 4; ++q) {
    float v0 = acc[0][q], v1 = acc[1][q], v2 = acc[2][q], v3 = acc[3][q];
    float m = fmaxf(fmaxf(v0, v1), fmaxf(v2, v3));
#pragma unroll
    for (int d = 1; d < 16; d <<= 1) m = fmaxf(m, __shfl_xor(m, d));
    float s = __expf(v0 - m) + __expf(v1 - m) + __expf(v2 - m) + __expf(v3 - m);
#pragma unroll
    for (int d = 1; d < 16; d <<= 1) s += __shfl_xor(s, d);
    float lse = m + __logf(s);
    int t = t0 + w * 16 + g * 4 + q;
    int a = actions[t];
    int acf = a >> 4;
    float vsel = (acf == 0) ? v0 : (acf == 1) ? v1 : (acf == 2) ? v2 : v3;
    if (c == (a & 15)) pe[t * 64 + b] = __expf(vsel - lse);
  }
}

// ---------------- start/stop GEMM + fused softmax/sigmoid ----------------
// grid: 129 t-tiles of 64, block 256 (4 waves x 16 rows), K split in halves for LDS
__global__ __launch_bounds__(256) void small_gemm(
    const u16* __restrict__ s_bf, const u16* __restrict__ wsm_t,
    float* __restrict__ ps, float* __restrict__ pb, float* __restrict__ pc) {
  __shared__ uint4 ldsA[64 * 16];    // 64 rows x 128 k
  __shared__ uint4 ldsB[192 * 16];   // 192 cols x 128 k
  const int t0 = blockIdx.x * 64;
  const int tid = threadIdx.x;
  const int lane = tid & 63, w = tid >> 6;
  const int g = lane >> 4, c = lane & 15;

  f32x4 acc[12];
#pragma unroll
  for (int i = 0; i < 12; ++i) acc[i] = (f32x4){0.f, 0.f, 0.f, 0.f};

  for (int kh = 0; kh < 2; ++kh) {
    if (kh) __syncthreads();
    for (int i = tid; i < 64 * 16; i += 256) {
      int row = i >> 4, u = i & 15;
      ldsA[(row * 16 + u) ^ (row & 7)] =
          *(const uint4*)(s_bf + (size_t)(t0 + row) * 256 + kh * 128 + u * 8);
    }
    for (int i = tid; i < 192 * 16; i += 256) {
      int row = i >> 4, u = i & 15;
      ldsB[(row * 16 + u) ^ (row & 7)] =
          *(const uint4*)(wsm_t + (size_t)row * 256 + kh * 128 + u * 8);
    }
    __syncthreads();
#pragma unroll
    for (int kk = 0; kk < 4; ++kk) {
      int u = kk * 4 + g;
      int arow = w * 16 + c;
      bf16x8 af = *(const bf16x8*)&ldsA[(arow * 16 + u) ^ (arow & 7)];
#pragma unroll
      for (int cf = 0; cf < 12; ++cf) {
        int brow = cf * 16 + c;
        bf16x8 bfr = *(const bf16x8*)&ldsB[(brow * 16 + u) ^ (brow & 7)];
        acc[cf] = __builtin_amdgcn_mfma_f32_16x16x32_bf16(af, bfr, acc[cf], 0, 0, 0);
      }
    }
  }

#pragma unroll
  for (int q = 0; q < 4; ++q) {
    int t = t0 + w * 16 + g * 4 + q;
    // start softmax over cols 0..63
    float v0 = acc[0][q], v1 = acc[1][q], v2 = acc[2][q], v3 = acc[3][q];
    float m = fmaxf(fmaxf(v0, v1), fmaxf(v2, v3));
#pragma unroll
    for (int d = 1; d < 16; d <<= 1) m = fmaxf(m, __shfl_xor(m, d));
    float s = __expf(v0 - m) + __expf(v1 - m) + __expf(v2 - m) + __expf(v3 - m);
#pragma unroll
    for (int d = 1; d < 16; d <<= 1) s += __shfl_xor(s, d);
    float lse = m + __logf(s);
    if (t <= T_LEN) {
      ps[t * 64 + 0 * 16 + c] = __expf(v0 - lse);
      ps[t * 64 + 1 * 16 + c] = __expf(v1 - lse);
      ps[t * 64 + 2 * 16 + c] = __expf(v2 - lse);
      ps[t * 64 + 3 * 16 + c] = __expf(v3 - lse);
#pragma unroll
      for (int bf = 0; bf < 4; ++bf) {
        float l0 = acc[4 + bf][q], l1 = acc[8 + bf][q];
        float d01 = l0 - l1;
        pb[t * 64 + bf * 16 + c] = 1.f / (1.f + __expf(-d01));
        pc[t * 64 + bf * 16 + c] = 1.f / (1.f + __expf(d01));
      }
    }
  }
}

// ---------------- chunked scan: per-chunk 64x64 transfer matrix ----------------
// lane k holds column k of M (M[j] regs). Step t: M <- A_t M with
// A_t = diag(e)*(s b^T + diag(c)):  w[k]=sum_j b[j]M[j][k];  M'[j][k]=e[j]*(s[j]w + c[j]M[j][k])
__global__ __launch_bounds__(64) void chunk_kernel(
    const float* __restrict__ pe, const float* __restrict__ ps,
    const float* __restrict__ pb, const float* __restrict__ pc,
    float* __restrict__ Mout, float* __restrict__ lscale) {
  const int ck = blockIdx.x;
  const int lane = threadIdx.x;
  float M[64];
#pragma unroll
  for (int j = 0; j < 64; ++j) M[j] = (j == lane) ? 1.f : 0.f;
  float lsc = 0.f;
  const int tlo = ck * 64 + 1;
  const int thi = min(ck * 64 + 64, T_LEN - 1);
  for (int t = tlo; t <= thi; ++t) {
    const float* br = pb + t * 64;
    const float* er = pe + t * 64;
    const float* sr = ps + t * 64;
    const float* cr = pc + t * 64;
    float wv = 0.f;
#pragma unroll
    for (int j = 0; j < 64; ++j) wv = fmaf(br[j], M[j], wv);
#pragma unroll
    for (int j = 0; j < 64; ++j) {
      float t1 = sr[j] * wv;
      float t2 = fmaf(cr[j], M[j], t1);
      M[j] = er[j] * t2;
    }
    if (((t - tlo) & 3) == 3) {
      float mx = M[0];
#pragma unroll
      for (int j = 1; j < 64; ++j) mx = fmaxf(mx, M[j]);
#pragma unroll
      for (int d = 1; d < 64; d <<= 1) mx = fmaxf(mx, __shfl_xor(mx, d));
      float inv = 1.f / mx;
#pragma unroll
      for (int j = 0; j < 64; ++j) M[j] *= inv;
      lsc += __logf(mx);
    }
  }
  // transpose via LDS -> store column-major [k][j] for coalesced combine loads
  __shared__ float xp[64 * 65];
#pragma unroll
  for (int j = 0; j < 64; ++j) xp[lane * 65 + j] = M[j];
  __syncthreads();
  float* out = Mout + ck * 4096;
  for (int i = 0; i < 64; ++i) out[i * 64 + lane] = xp[i * 65 + lane];
  if (lane == 0) lscale[ck] = lsc;
}

// ---------------- sequential combine over 128 chunks ----------------
__global__ __launch_bounds__(64) void combine_kernel(
    const float* __restrict__ Mout, const float* __restrict__ lscale,
    const float* __restrict__ pe, const float* __restrict__ ps,
    const float* __restrict__ pb, float* __restrict__ out) {
  const int lane = threadIdx.x;
  __shared__ float vsh[64];
  float v = ps[lane] * pe[lane];   // f0 = start_logps[0] + emit[0]
  double lsc = 0.0;
  for (int cph = 0; cph < 128; ++cph) {
    vsh[lane] = v;
    __syncthreads();
    const float* Mc = Mout + cph * 4096;
    float u0 = 0.f, u1 = 0.f, u2 = 0.f, u3 = 0.f;
#pragma unroll
    for (int k = 0; k < 64; k += 4) {
      u0 = fmaf(vsh[k + 0], Mc[(k + 0) * 64 + lane], u0);
      u1 = fmaf(vsh[k + 1], Mc[(k + 1) * 64 + lane], u1);
      u2 = fmaf(vsh[k + 2], Mc[(k + 2) * 64 + lane], u2);
      u3 = fmaf(vsh[k + 3], Mc[(k + 3) * 64 + lane], u3);
    }
    float u = (u0 + u1) + (u2 + u3);
    float mx = u;
#pragma unroll
    for (int d = 1; d < 64; d <<= 1) mx = fmaxf(mx, __shfl_xor(mx, d));
    v = u / mx;
    lsc += (double)__logf(mx) + (double)lscale[cph];
    __syncthreads();
  }
  float z = v * pb[T_LEN * 64 + lane];   // stop prob at t=T
#pragma unroll
  for (int d = 1; d < 64; d <<= 1) z += __shfl_xor(z, d);
  if (lane == 0) out[0] = (float)(-((double)logf(z) + lsc));
}

extern "C" void kernel_launch(void* const* d_in, const int* in_sizes, int n_in,
                              void* d_out, int out_size, void* d_ws, size_t ws_size,
                              hipStream_t stream) {
  const float* s_i      = (const float*)d_in[0];
  const float* W_action = (const float*)d_in[1];
  const float* W_stop   = (const float*)d_in[2];
  const float* W_start  = (const float*)d_in[3];
  const int*   actions  = (const int*)d_in[4];

  char* ws = (char*)d_ws;
  u16*   s_bf  = (u16*)(ws + WS_SBF);
  u16*   wa_t  = (u16*)(ws + WS_WAT);
  u16*   wsm_t = (u16*)(ws + WS_WSMT);
  float* pe    = (float*)(ws + WS_PE);
  float* ps    = (float*)(ws + WS_PS);
  float* pb    = (float*)(ws + WS_PB);
  float* pc    = (float*)(ws + WS_PC);
  float* Mout  = (float*)(ws + WS_MOUT);
  float* lsc   = (float*)(ws + WS_LSC);

  conv_s<<<8256, 256, 0, stream>>>(s_i, s_bf);
  conv_wa<<<4096, 256, 0, stream>>>(W_action, wa_t);
  conv_wsm<<<192, 256, 0, stream>>>(W_stop, W_start, wsm_t);
  small_gemm<<<129, 256, 0, stream>>>(s_bf, wsm_t, ps, pb, pc);
  act_gemm<<<dim3(64, 128), 256, 0, stream>>>(s_bf, wa_t, actions, pe);
  chunk_kernel<<<128, 64, 0, stream>>>(pe, ps, pb, pc, Mout, lsc);
  combine_kernel<<<1, 64, 0, stream>>>(Mout, lsc, pe, ps, pb, (float*)d_out);
}

// Round 4
// 311.947 us; speedup vs baseline: 1.3686x; 1.3686x over previous
//
#include <hip/hip_runtime.h>
#include <stdint.h>

// HMM trajectory-net forward:  -logsumexp over an 8191-step 64-state HMM scan.
// Pipeline:
//   conv_*       : fp32 -> bf16 repacks
//   small_gemm   : start/stop logits via MFMA, fused softmax/sigmoid -> ps, pb, pc
//   act_gemm     : action logits via MFMA, fused row-logsumexp + action-select -> pe
//   chunk_kernel : 128 chunks x 64 steps; per-chunk 64x64 transfer matrix in registers
//   group_combine: 16 blocks, each folds 8 chunk matrices via fp32 matmul chain (parallel)
//   final_combine: 16 sequential mat-vecs (4-wave split) + boundary terms -> scalar

typedef short bf16x8 __attribute__((ext_vector_type(8)));
typedef float f32x4  __attribute__((ext_vector_type(4)));
typedef unsigned short u16;

#define T_LEN 8192
#define SDIM  256

// ---- workspace layout (bytes) ----
#define WS_SBF    0              // 8256*256 bf16 (padded rows zeroed)
#define WS_WAT    4227072        // 4096*256 bf16  [b*64+n][s]
#define WS_WSMT   6324224        // 192*256 bf16   [col][s]
#define WS_PE     6422528        // 8192*64 f32
#define WS_PS     8519680        // 8193*64 f32
#define WS_PB     10617088       // 8193*64 f32
#define WS_PC     12714496       // 8193*64 f32   (dead after chunk_kernel -> reused for Gout)
#define WS_MOUT   14811904       // 128*4096 f32  [chunk][k][j]
#define WS_LSC    16909056       // 128 f32
#define WS_GOUT   WS_PC                      // 16*4096 f32 (reuses pc region)
#define WS_GLSC   (WS_PC + 262144)           // 16 f32

__device__ inline u16 f2bf(float f) {
  union { float f; uint32_t u; } v; v.f = f;
  uint32_t u = v.u;
  return (u16)((u + 0x7fffu + ((u >> 16) & 1u)) >> 16);
}

// ---------------- converts ----------------
__global__ void conv_s(const float* __restrict__ s_i, u16* __restrict__ s_bf) {
  int idx = blockIdx.x * 256 + threadIdx.x;
  int t = idx >> 8;
  float v = (t < T_LEN + 1) ? s_i[idx] : 0.f;
  s_bf[idx] = f2bf(v);
}

__global__ void conv_wa(const float* __restrict__ Wa, u16* __restrict__ wa_t) {
  int idx = blockIdx.x * 256 + threadIdx.x;
  int s = idx >> 12, bn = idx & 4095;
  wa_t[bn * 256 + s] = f2bf(Wa[idx]);
}

__global__ void conv_wsm(const float* __restrict__ Wstop, const float* __restrict__ Wstart,
                         u16* __restrict__ wsm_t) {
  int idx = blockIdx.x * 256 + threadIdx.x;
  int col = idx >> 8, s = idx & 255;
  float v;
  if (col < 64)       v = Wstart[s * 64 + col];
  else if (col < 128) v = Wstop[s * 128 + (col - 64) * 2 + 0];
  else                v = Wstop[s * 128 + (col - 128) * 2 + 1];
  wsm_t[col * 256 + s] = f2bf(v);
}

// ---------------- action GEMM + fused emit ----------------
__global__ __launch_bounds__(256) void act_gemm(
    const u16* __restrict__ s_bf, const u16* __restrict__ wa_t,
    const int* __restrict__ actions, float* __restrict__ pe) {
  __shared__ uint4 ldsA[64 * 32];
  __shared__ uint4 ldsB[64 * 32];
  const int b  = blockIdx.x;
  const int t0 = blockIdx.y * 64;
  const int tid = threadIdx.x;

  for (int i = tid; i < 64 * 32; i += 256) {
    int row = i >> 5, u = i & 31;
    ldsA[(row * 32 + u) ^ (row & 7)] =
        *(const uint4*)(s_bf + (size_t)(t0 + row) * 256 + u * 8);
    ldsB[(row * 32 + u) ^ (row & 7)] =
        *(const uint4*)(wa_t + (size_t)(b * 64 + row) * 256 + u * 8);
  }
  __syncthreads();

  const int lane = tid & 63, w = tid >> 6;
  const int g = lane >> 4, c = lane & 15;
  f32x4 acc[4];
#pragma unroll
  for (int i = 0; i < 4; ++i) acc[i] = (f32x4){0.f, 0.f, 0.f, 0.f};

#pragma unroll
  for (int kk = 0; kk < 8; ++kk) {
    int u = kk * 4 + g;
    int arow = w * 16 + c;
    bf16x8 af = *(const bf16x8*)&ldsA[(arow * 32 + u) ^ (arow & 7)];
#pragma unroll
    for (int cf = 0; cf < 4; ++cf) {
      int brow = cf * 16 + c;
      bf16x8 bfr = *(const bf16x8*)&ldsB[(brow * 32 + u) ^ (brow & 7)];
      acc[cf] = __builtin_amdgcn_mfma_f32_16x16x32_bf16(af, bfr, acc[cf], 0, 0, 0);
    }
  }

#pragma unroll
  for (int q = 0; q < 4; ++q) {
    float v0 = acc[0][q], v1 = acc[1][q], v2 = acc[2][q], v3 = acc[3][q];
    float m = fmaxf(fmaxf(v0, v1), fmaxf(v2, v3));
#pragma unroll
    for (int d = 1; d < 16; d <<= 1) m = fmaxf(m, __shfl_xor(m, d));
    float s = __expf(v0 - m) + __expf(v1 - m) + __expf(v2 - m) + __expf(v3 - m);
#pragma unroll
    for (int d = 1; d < 16; d <<= 1) s += __shfl_xor(s, d);
    float lse = m + __logf(s);
    int t = t0 + w * 16 + g * 4 + q;
    int a = actions[t];
    int acf = a >> 4;
    float vsel = (acf == 0) ? v0 : (acf == 1) ? v1 : (acf == 2) ? v2 : v3;
    if (c == (a & 15)) pe[t * 64 + b] = __expf(vsel - lse);
  }
}

// ---------------- start/stop GEMM + fused softmax/sigmoid ----------------
__global__ __launch_bounds__(256) void small_gemm(
    const u16* __restrict__ s_bf, const u16* __restrict__ wsm_t,
    float* __restrict__ ps, float* __restrict__ pb, float* __restrict__ pc) {
  __shared__ uint4 ldsA[64 * 16];
  __shared__ uint4 ldsB[192 * 16];
  const int t0 = blockIdx.x * 64;
  const int tid = threadIdx.x;
  const int lane = tid & 63, w = tid >> 6;
  const int g = lane >> 4, c = lane & 15;

  f32x4 acc[12];
#pragma unroll
  for (int i = 0; i < 12; ++i) acc[i] = (f32x4){0.f, 0.f, 0.f, 0.f};

  for (int kh = 0; kh < 2; ++kh) {
    if (kh) __syncthreads();
    for (int i = tid; i < 64 * 16; i += 256) {
      int row = i >> 4, u = i & 15;
      ldsA[(row * 16 + u) ^ (row & 7)] =
          *(const uint4*)(s_bf + (size_t)(t0 + row) * 256 + kh * 128 + u * 8);
    }
    for (int i = tid; i < 192 * 16; i += 256) {
      int row = i >> 4, u = i & 15;
      ldsB[(row * 16 + u) ^ (row & 7)] =
          *(const uint4*)(wsm_t + (size_t)row * 256 + kh * 128 + u * 8);
    }
    __syncthreads();
#pragma unroll
    for (int kk = 0; kk < 4; ++kk) {
      int u = kk * 4 + g;
      int arow = w * 16 + c;
      bf16x8 af = *(const bf16x8*)&ldsA[(arow * 16 + u) ^ (arow & 7)];
#pragma unroll
      for (int cf = 0; cf < 12; ++cf) {
        int brow = cf * 16 + c;
        bf16x8 bfr = *(const bf16x8*)&ldsB[(brow * 16 + u) ^ (brow & 7)];
        acc[cf] = __builtin_amdgcn_mfma_f32_16x16x32_bf16(af, bfr, acc[cf], 0, 0, 0);
      }
    }
  }

#pragma unroll
  for (int q = 0; q < 4; ++q) {
    int t = t0 + w * 16 + g * 4 + q;
    float v0 = acc[0][q], v1 = acc[1][q], v2 = acc[2][q], v3 = acc[3][q];
    float m = fmaxf(fmaxf(v0, v1), fmaxf(v2, v3));
#pragma unroll
    for (int d = 1; d < 16; d <<= 1) m = fmaxf(m, __shfl_xor(m, d));
    float s = __expf(v0 - m) + __expf(v1 - m) + __expf(v2 - m) + __expf(v3 - m);
#pragma unroll
    for (int d = 1; d < 16; d <<= 1) s += __shfl_xor(s, d);
    float lse = m + __logf(s);
    if (t <= T_LEN) {
      ps[t * 64 + 0 * 16 + c] = __expf(v0 - lse);
      ps[t * 64 + 1 * 16 + c] = __expf(v1 - lse);
      ps[t * 64 + 2 * 16 + c] = __expf(v2 - lse);
      ps[t * 64 + 3 * 16 + c] = __expf(v3 - lse);
#pragma unroll
      for (int bf = 0; bf < 4; ++bf) {
        float l0 = acc[4 + bf][q], l1 = acc[8 + bf][q];
        float d01 = l0 - l1;
        pb[t * 64 + bf * 16 + c] = 1.f / (1.f + __expf(-d01));
        pc[t * 64 + bf * 16 + c] = 1.f / (1.f + __expf(d01));
      }
    }
  }
}

// ---------------- chunked scan: per-chunk 64x64 transfer matrix ----------------
__global__ __launch_bounds__(64) void chunk_kernel(
    const float* __restrict__ pe, const float* __restrict__ ps,
    const float* __restrict__ pb, const float* __restrict__ pc,
    float* __restrict__ Mout, float* __restrict__ lscale) {
  const int ck = blockIdx.x;
  const int lane = threadIdx.x;
  float M[64];
#pragma unroll
  for (int j = 0; j < 64; ++j) M[j] = (j == lane) ? 1.f : 0.f;
  float lsc = 0.f;
  const int tlo = ck * 64 + 1;
  const int thi = min(ck * 64 + 64, T_LEN - 1);
  for (int t = tlo; t <= thi; ++t) {
    const float* br = pb + t * 64;
    const float* er = pe + t * 64;
    const float* sr = ps + t * 64;
    const float* cr = pc + t * 64;
    float wv = 0.f;
#pragma unroll
    for (int j = 0; j < 64; ++j) wv = fmaf(br[j], M[j], wv);
#pragma unroll
    for (int j = 0; j < 64; ++j) {
      float t1 = sr[j] * wv;
      float t2 = fmaf(cr[j], M[j], t1);
      M[j] = er[j] * t2;
    }
    if (((t - tlo) & 3) == 3) {
      float mx = M[0];
#pragma unroll
      for (int j = 1; j < 64; ++j) mx = fmaxf(mx, M[j]);
#pragma unroll
      for (int d = 1; d < 64; d <<= 1) mx = fmaxf(mx, __shfl_xor(mx, d));
      float inv = 1.f / mx;
#pragma unroll
      for (int j = 0; j < 64; ++j) M[j] *= inv;
      lsc += __logf(mx);
    }
  }
  __shared__ float xp[64 * 65];
#pragma unroll
  for (int j = 0; j < 64; ++j) xp[lane * 65 + j] = M[j];
  __syncthreads();
  float* out = Mout + ck * 4096;
  for (int i = 0; i < 64; ++i) out[i * 64 + lane] = xp[i * 65 + lane];
  if (lane == 0) lscale[ck] = lsc;
}

// ---------------- level-1 combine: 16 groups x 8 chunk matrices ----------------
// Mout[ck][i][j] = M_ck[j][i].  Block g computes G = M_{8g+7} * ... * M_{8g},
// renormalizing (max->1) after each multiply.  Gout same layout as Mout.
__global__ __launch_bounds__(256) void group_combine(
    const float* __restrict__ Mout, const float* __restrict__ lscale,
    float* __restrict__ Gout, float* __restrict__ glsc) {
  const int g = blockIdx.x;
  const int tid = threadIdx.x;
  const int j = tid & 63;        // output row
  const int w = tid >> 6;        // wave -> column group [w*16, w*16+16)
  __shared__ float Xa[64 * 68];  // X[r][c] at Xa[r*68+c]; stride 68 keeps float4 alignment
  __shared__ float Xb[64 * 68];
  __shared__ float red[4];

  const float* M0 = Mout + (size_t)(8 * g) * 4096;
  for (int idx = tid; idx < 4096; idx += 256) {
    int i = idx >> 6, r = idx & 63;          // M0[i*64+r] = M[r][i]
    Xa[r * 68 + i] = M0[idx];
  }
  __syncthreads();

  float lsc = 0.f;
  float* Xcur = Xa;
  float* Xnxt = Xb;

  for (int m = 1; m < 8; ++m) {
    const float* Mc = Mout + (size_t)(8 * g + m) * 4096;
    float acc[16];
#pragma unroll
    for (int i = 0; i < 16; ++i) acc[i] = 0.f;

    for (int k = 0; k < 64; ++k) {
      float mv = Mc[k * 64 + j];                       // M_m[j][k], coalesced
      const float* xr = Xcur + k * 68 + (w << 4);      // wave-uniform broadcast
      float4 x0 = *(const float4*)(xr + 0);
      float4 x1 = *(const float4*)(xr + 4);
      float4 x2 = *(const float4*)(xr + 8);
      float4 x3 = *(const float4*)(xr + 12);
      acc[0]  = fmaf(mv, x0.x, acc[0]);  acc[1]  = fmaf(mv, x0.y, acc[1]);
      acc[2]  = fmaf(mv, x0.z, acc[2]);  acc[3]  = fmaf(mv, x0.w, acc[3]);
      acc[4]  = fmaf(mv, x1.x, acc[4]);  acc[5]  = fmaf(mv, x1.y, acc[5]);
      acc[6]  = fmaf(mv, x1.z, acc[6]);  acc[7]  = fmaf(mv, x1.w, acc[7]);
      acc[8]  = fmaf(mv, x2.x, acc[8]);  acc[9]  = fmaf(mv, x2.y, acc[9]);
      acc[10] = fmaf(mv, x2.z, acc[10]); acc[11] = fmaf(mv, x2.w, acc[11]);
      acc[12] = fmaf(mv, x3.x, acc[12]); acc[13] = fmaf(mv, x3.y, acc[13]);
      acc[14] = fmaf(mv, x3.z, acc[14]); acc[15] = fmaf(mv, x3.w, acc[15]);
    }

    // block-wide max (entries all > 0)
    float lm = acc[0];
#pragma unroll
    for (int i = 1; i < 16; ++i) lm = fmaxf(lm, acc[i]);
#pragma unroll
    for (int d = 1; d < 64; d <<= 1) lm = fmaxf(lm, __shfl_xor(lm, d));
    if ((tid & 63) == 0) red[w] = lm;
    __syncthreads();
    float bm = fmaxf(fmaxf(red[0], red[1]), fmaxf(red[2], red[3]));
    float inv = 1.f / bm;
    lsc += __logf(bm);
#pragma unroll
    for (int i = 0; i < 16; ++i)
      Xnxt[j * 68 + (w << 4) + i] = acc[i] * inv;
    __syncthreads();
    float* t = Xcur; Xcur = Xnxt; Xnxt = t;
  }

  // store G: Gout[g][i][r] = G[r][i]
  float* out = Gout + (size_t)g * 4096;
  for (int idx = tid; idx < 4096; idx += 256) {
    int i = idx >> 6, r = idx & 63;
    out[idx] = Xcur[r * 68 + i];
  }
  if (tid == 0) {
    float s = lsc;
#pragma unroll
    for (int m = 0; m < 8; ++m) s += lscale[8 * g + m];
    glsc[g] = s;
  }
}

// ---------------- level-2 combine: 16 sequential mat-vecs ----------------
__global__ __launch_bounds__(256) void final_combine(
    const float* __restrict__ Gout, const float* __restrict__ glsc,
    const float* __restrict__ pe, const float* __restrict__ ps,
    const float* __restrict__ pb, float* __restrict__ out) {
  const int tid = threadIdx.x;
  const int j = tid & 63, w = tid >> 6;
  __shared__ float vsh[64];
  __shared__ float part[4 * 64];
  if (tid < 64) vsh[tid] = ps[tid] * pe[tid];   // f0
  __syncthreads();
  double lsc = 0.0;
  for (int gph = 0; gph < 16; ++gph) {
    const float* Gc = Gout + (size_t)gph * 4096;
    const int k0 = w << 4;
    float a0 = 0.f, a1 = 0.f, a2 = 0.f, a3 = 0.f;
#pragma unroll
    for (int kk = 0; kk < 16; kk += 4) {
      a0 = fmaf(vsh[k0 + kk + 0], Gc[(k0 + kk + 0) * 64 + j], a0);
      a1 = fmaf(vsh[k0 + kk + 1], Gc[(k0 + kk + 1) * 64 + j], a1);
      a2 = fmaf(vsh[k0 + kk + 2], Gc[(k0 + kk + 2) * 64 + j], a2);
      a3 = fmaf(vsh[k0 + kk + 3], Gc[(k0 + kk + 3) * 64 + j], a3);
    }
    part[w * 64 + j] = (a0 + a1) + (a2 + a3);
    __syncthreads();
    if (w == 0) {
      float u = part[j] + part[64 + j] + part[128 + j] + part[192 + j];
      float mx = u;
#pragma unroll
      for (int d = 1; d < 64; d <<= 1) mx = fmaxf(mx, __shfl_xor(mx, d));
      vsh[j] = u / mx;
      lsc += (double)__logf(mx) + (double)glsc[gph];
    }
    __syncthreads();
  }
  if (w == 0) {
    float z = vsh[j] * pb[T_LEN * 64 + j];
#pragma unroll
    for (int d = 1; d < 64; d <<= 1) z += __shfl_xor(z, d);
    if (j == 0) out[0] = (float)(-((double)logf(z) + lsc));
  }
}

extern "C" void kernel_launch(void* const* d_in, const int* in_sizes, int n_in,
                              void* d_out, int out_size, void* d_ws, size_t ws_size,
                              hipStream_t stream) {
  const float* s_i      = (const float*)d_in[0];
  const float* W_action = (const float*)d_in[1];
  const float* W_stop   = (const float*)d_in[2];
  const float* W_start  = (const float*)d_in[3];
  const int*   actions  = (const int*)d_in[4];

  char* ws = (char*)d_ws;
  u16*   s_bf  = (u16*)(ws + WS_SBF);
  u16*   wa_t  = (u16*)(ws + WS_WAT);
  u16*   wsm_t = (u16*)(ws + WS_WSMT);
  float* pe    = (float*)(ws + WS_PE);
  float* ps    = (float*)(ws + WS_PS);
  float* pb    = (float*)(ws + WS_PB);
  float* pc    = (float*)(ws + WS_PC);
  float* Mout  = (float*)(ws + WS_MOUT);
  float* lsc   = (float*)(ws + WS_LSC);
  float* Gout  = (float*)(ws + WS_GOUT);
  float* glsc  = (float*)(ws + WS_GLSC);

  conv_s<<<8256, 256, 0, stream>>>(s_i, s_bf);
  conv_wa<<<4096, 256, 0, stream>>>(W_action, wa_t);
  conv_wsm<<<192, 256, 0, stream>>>(W_stop, W_start, wsm_t);
  small_gemm<<<129, 256, 0, stream>>>(s_bf, wsm_t, ps, pb, pc);
  act_gemm<<<dim3(64, 128), 256, 0, stream>>>(s_bf, wa_t, actions, pe);
  chunk_kernel<<<128, 64, 0, stream>>>(pe, ps, pb, pc, Mout, lsc);
  group_combine<<<16, 256, 0, stream>>>(Mout, lsc, Gout, glsc);
  final_combine<<<1, 256, 0, stream>>>(Gout, glsc, pe, ps, pb, (float*)d_out);
}

// Round 6
// 300.550 us; speedup vs baseline: 1.4205x; 1.0379x over previous
//
#include <hip/hip_runtime.h>
#include <stdint.h>

// HMM trajectory-net forward:  -logsumexp over an 8191-step 64-state HMM scan.
// Pipeline:
//   conv_*       : fp32 -> bf16 repacks
//   small_gemm   : start/stop logits via MFMA, fused softmax/sigmoid -> ps, pb, pc
//   act_gemm     : action logits via MFMA, fused row-logsumexp + action-select -> pe
//   chunk_kernel : 128 chunks x 64 steps; per-chunk 64x64 transfer matrix in registers
//                  (coalesced per-lane loads + readlane broadcast, reg double-buffer)
//   group_combine: 16 blocks, each folds 8 chunk matrices via fp32 matmul chain (parallel)
//   final_combine: 16 sequential mat-vecs (4-wave split) + boundary terms -> scalar

typedef short bf16x8 __attribute__((ext_vector_type(8)));
typedef float f32x4  __attribute__((ext_vector_type(4)));
typedef unsigned short u16;

#define T_LEN 8192
#define SDIM  256

// ---- workspace layout (bytes) ----
#define WS_SBF    0              // 8256*256 bf16 (padded rows zeroed)
#define WS_WAT    4227072        // 4096*256 bf16  [b*64+n][s]
#define WS_WSMT   6324224        // 192*256 bf16   [col][s]
#define WS_PE     6422528        // 8192*64 f32
#define WS_PS     8519680        // 8193*64 f32
#define WS_PB     10617088       // 8193*64 f32
#define WS_PC     12714496       // 8193*64 f32   (dead after chunk_kernel -> reused for Gout)
#define WS_MOUT   14811904       // 128*4096 f32  [chunk][k][j]
#define WS_LSC    16909056       // 128 f32
#define WS_GOUT   WS_PC                      // 16*4096 f32 (reuses pc region)
#define WS_GLSC   (WS_PC + 262144)           // 16 f32

__device__ inline u16 f2bf(float f) {
  union { float f; uint32_t u; } v; v.f = f;
  uint32_t u = v.u;
  return (u16)((u + 0x7fffu + ((u >> 16) & 1u)) >> 16);
}

// ---------------- converts ----------------
__global__ void conv_s(const float* __restrict__ s_i, u16* __restrict__ s_bf) {
  int idx = blockIdx.x * 256 + threadIdx.x;
  int t = idx >> 8;
  float v = (t < T_LEN + 1) ? s_i[idx] : 0.f;
  s_bf[idx] = f2bf(v);
}

__global__ void conv_wa(const float* __restrict__ Wa, u16* __restrict__ wa_t) {
  int idx = blockIdx.x * 256 + threadIdx.x;
  int s = idx >> 12, bn = idx & 4095;
  wa_t[bn * 256 + s] = f2bf(Wa[idx]);
}

__global__ void conv_wsm(const float* __restrict__ Wstop, const float* __restrict__ Wstart,
                         u16* __restrict__ wsm_t) {
  int idx = blockIdx.x * 256 + threadIdx.x;
  int col = idx >> 8, s = idx & 255;
  float v;
  if (col < 64)       v = Wstart[s * 64 + col];
  else if (col < 128) v = Wstop[s * 128 + (col - 64) * 2 + 0];
  else                v = Wstop[s * 128 + (col - 128) * 2 + 1];
  wsm_t[col * 256 + s] = f2bf(v);
}

// ---------------- action GEMM + fused emit ----------------
__global__ __launch_bounds__(256) void act_gemm(
    const u16* __restrict__ s_bf, const u16* __restrict__ wa_t,
    const int* __restrict__ actions, float* __restrict__ pe) {
  __shared__ uint4 ldsA[64 * 32];
  __shared__ uint4 ldsB[64 * 32];
  const int b  = blockIdx.x;
  const int t0 = blockIdx.y * 64;
  const int tid = threadIdx.x;

  for (int i = tid; i < 64 * 32; i += 256) {
    int row = i >> 5, u = i & 31;
    ldsA[(row * 32 + u) ^ (row & 7)] =
        *(const uint4*)(s_bf + (size_t)(t0 + row) * 256 + u * 8);
    ldsB[(row * 32 + u) ^ (row & 7)] =
        *(const uint4*)(wa_t + (size_t)(b * 64 + row) * 256 + u * 8);
  }
  __syncthreads();

  const int lane = tid & 63, w = tid >> 6;
  const int g = lane >> 4, c = lane & 15;
  f32x4 acc[4];
#pragma unroll
  for (int i = 0; i < 4; ++i) acc[i] = (f32x4){0.f, 0.f, 0.f, 0.f};

#pragma unroll
  for (int kk = 0; kk < 8; ++kk) {
    int u = kk * 4 + g;
    int arow = w * 16 + c;
    bf16x8 af = *(const bf16x8*)&ldsA[(arow * 32 + u) ^ (arow & 7)];
#pragma unroll
    for (int cf = 0; cf < 4; ++cf) {
      int brow = cf * 16 + c;
      bf16x8 bfr = *(const bf16x8*)&ldsB[(brow * 32 + u) ^ (brow & 7)];
      acc[cf] = __builtin_amdgcn_mfma_f32_16x16x32_bf16(af, bfr, acc[cf], 0, 0, 0);
    }
  }

#pragma unroll
  for (int q = 0; q < 4; ++q) {
    float v0 = acc[0][q], v1 = acc[1][q], v2 = acc[2][q], v3 = acc[3][q];
    float m = fmaxf(fmaxf(v0, v1), fmaxf(v2, v3));
#pragma unroll
    for (int d = 1; d < 16; d <<= 1) m = fmaxf(m, __shfl_xor(m, d));
    float s = __expf(v0 - m) + __expf(v1 - m) + __expf(v2 - m) + __expf(v3 - m);
#pragma unroll
    for (int d = 1; d < 16; d <<= 1) s += __shfl_xor(s, d);
    float lse = m + __logf(s);
    int t = t0 + w * 16 + g * 4 + q;
    int a = actions[t];
    int acf = a >> 4;
    float vsel = (acf == 0) ? v0 : (acf == 1) ? v1 : (acf == 2) ? v2 : v3;
    if (c == (a & 15)) pe[t * 64 + b] = __expf(vsel - lse);
  }
}

// ---------------- start/stop GEMM + fused softmax/sigmoid ----------------
__global__ __launch_bounds__(256) void small_gemm(
    const u16* __restrict__ s_bf, const u16* __restrict__ wsm_t,
    float* __restrict__ ps, float* __restrict__ pb, float* __restrict__ pc) {
  __shared__ uint4 ldsA[64 * 16];
  __shared__ uint4 ldsB[192 * 16];
  const int t0 = blockIdx.x * 64;
  const int tid = threadIdx.x;
  const int lane = tid & 63, w = tid >> 6;
  const int g = lane >> 4, c = lane & 15;

  f32x4 acc[12];
#pragma unroll
  for (int i = 0; i < 12; ++i) acc[i] = (f32x4){0.f, 0.f, 0.f, 0.f};

  for (int kh = 0; kh < 2; ++kh) {
    if (kh) __syncthreads();
    for (int i = tid; i < 64 * 16; i += 256) {
      int row = i >> 4, u = i & 15;
      ldsA[(row * 16 + u) ^ (row & 7)] =
          *(const uint4*)(s_bf + (size_t)(t0 + row) * 256 + kh * 128 + u * 8);
    }
    for (int i = tid; i < 192 * 16; i += 256) {
      int row = i >> 4, u = i & 15;
      ldsB[(row * 16 + u) ^ (row & 7)] =
          *(const uint4*)(wsm_t + (size_t)row * 256 + kh * 128 + u * 8);
    }
    __syncthreads();
#pragma unroll
    for (int kk = 0; kk < 4; ++kk) {
      int u = kk * 4 + g;
      int arow = w * 16 + c;
      bf16x8 af = *(const bf16x8*)&ldsA[(arow * 16 + u) ^ (arow & 7)];
#pragma unroll
      for (int cf = 0; cf < 12; ++cf) {
        int brow = cf * 16 + c;
        bf16x8 bfr = *(const bf16x8*)&ldsB[(brow * 16 + u) ^ (brow & 7)];
        acc[cf] = __builtin_amdgcn_mfma_f32_16x16x32_bf16(af, bfr, acc[cf], 0, 0, 0);
      }
    }
  }

#pragma unroll
  for (int q = 0; q < 4; ++q) {
    int t = t0 + w * 16 + g * 4 + q;
    float v0 = acc[0][q], v1 = acc[1][q], v2 = acc[2][q], v3 = acc[3][q];
    float m = fmaxf(fmaxf(v0, v1), fmaxf(v2, v3));
#pragma unroll
    for (int d = 1; d < 16; d <<= 1) m = fmaxf(m, __shfl_xor(m, d));
    float s = __expf(v0 - m) + __expf(v1 - m) + __expf(v2 - m) + __expf(v3 - m);
#pragma unroll
    for (int d = 1; d < 16; d <<= 1) s += __shfl_xor(s, d);
    float lse = m + __logf(s);
    if (t <= T_LEN) {
      ps[t * 64 + 0 * 16 + c] = __expf(v0 - lse);
      ps[t * 64 + 1 * 16 + c] = __expf(v1 - lse);
      ps[t * 64 + 2 * 16 + c] = __expf(v2 - lse);
      ps[t * 64 + 3 * 16 + c] = __expf(v3 - lse);
#pragma unroll
      for (int bf = 0; bf < 4; ++bf) {
        float l0 = acc[4 + bf][q], l1 = acc[8 + bf][q];
        float d01 = l0 - l1;
        pb[t * 64 + bf * 16 + c] = 1.f / (1.f + __expf(-d01));
        pc[t * 64 + bf * 16 + c] = 1.f / (1.f + __expf(d01));
      }
    }
  }
}

// ---------------- chunked scan: per-chunk 64x64 transfer matrix ----------------
// lane k holds column k of M.  Step t: M <- A_t M with A_t = diag(e)*(s b^T + diag(c)).
// Per step, lane j loads its OWN (b, e*c, e*s) coalesced; the j-loop broadcasts them
// via __shfl with compile-time-constant lane -> v_readlane (no memory ops in loop).
// Loads are register-double-buffered one step ahead to hide latency.
__global__ __launch_bounds__(64) void chunk_kernel(
    const float* __restrict__ pe, const float* __restrict__ ps,
    const float* __restrict__ pb, const float* __restrict__ pc,
    float* __restrict__ Mout, float* __restrict__ lscale) {
  const int ck = blockIdx.x;
  const int lane = threadIdx.x;
  float M[64];
#pragma unroll
  for (int j = 0; j < 64; ++j) M[j] = (j == lane) ? 1.f : 0.f;
  float lsc = 0.f;
  const int tlo = ck * 64 + 1;
  const int thi = min(ck * 64 + 64, T_LEN - 1);

  // prefetch step tlo (lane j loads its own values: coalesced)
  float bv_n, ecv_n, esv_n;
  {
    int base = tlo * 64 + lane;
    float b = pb[base], e = pe[base], s = ps[base], c = pc[base];
    bv_n = b; ecv_n = e * c; esv_n = e * s;
  }

  for (int t = tlo; t <= thi; ++t) {
    float bv = bv_n, ecv = ecv_n, esv = esv_n;
    if (t < thi) {
      int base = (t + 1) * 64 + lane;
      float b = pb[base], e = pe[base], s = ps[base], c = pc[base];
      bv_n = b; ecv_n = e * c; esv_n = e * s;
    }
    // wv[k] = sum_j b[j] * M[j][k]   (4 split accumulators to break the fma chain)
    float w0 = 0.f, w1 = 0.f, w2 = 0.f, w3 = 0.f;
#pragma unroll
    for (int j = 0; j < 64; j += 4) {
      w0 = fmaf(__shfl(bv, j + 0), M[j + 0], w0);
      w1 = fmaf(__shfl(bv, j + 1), M[j + 1], w1);
      w2 = fmaf(__shfl(bv, j + 2), M[j + 2], w2);
      w3 = fmaf(__shfl(bv, j + 3), M[j + 3], w3);
    }
    float wv = (w0 + w1) + (w2 + w3);
    // M'[j][k] = ec[j]*M[j][k] + es[j]*wv[k]
#pragma unroll
    for (int j = 0; j < 64; ++j) {
      M[j] = fmaf(__shfl(ecv, j), M[j], __shfl(esv, j) * wv);
    }
    if (((t - tlo) & 7) == 7) {
      float mx = M[0];
#pragma unroll
      for (int j = 1; j < 64; ++j) mx = fmaxf(mx, M[j]);
#pragma unroll
      for (int d = 1; d < 64; d <<= 1) mx = fmaxf(mx, __shfl_xor(mx, d));
      float inv = 1.f / mx;
#pragma unroll
      for (int j = 0; j < 64; ++j) M[j] *= inv;
      lsc += __logf(mx);
    }
  }
  // transpose via LDS -> store column-major [k][j] for coalesced combine loads
  __shared__ float xp[64 * 65];
#pragma unroll
  for (int j = 0; j < 64; ++j) xp[lane * 65 + j] = M[j];
  __syncthreads();
  float* out = Mout + ck * 4096;
  for (int i = 0; i < 64; ++i) out[i * 64 + lane] = xp[i * 65 + lane];
  if (lane == 0) lscale[ck] = lsc;
}

// ---------------- level-1 combine: 16 groups x 8 chunk matrices ----------------
// Mout[ck][i][j] = M_ck[j][i].  Block g computes G = M_{8g+7} * ... * M_{8g},
// renormalizing (max->1) after each multiply.  Gout same layout as Mout.
__global__ __launch_bounds__(256) void group_combine(
    const float* __restrict__ Mout, const float* __restrict__ lscale,
    float* __restrict__ Gout, float* __restrict__ glsc) {
  const int g = blockIdx.x;
  const int tid = threadIdx.x;
  const int j = tid & 63;        // output row
  const int w = tid >> 6;        // wave -> column group [w*16, w*16+16)
  __shared__ float Xa[64 * 68];  // X[r][c] at Xa[r*68+c]; stride 68 keeps float4 alignment
  __shared__ float Xb[64 * 68];
  __shared__ float red[4];

  const float* M0 = Mout + (size_t)(8 * g) * 4096;
  for (int idx = tid; idx < 4096; idx += 256) {
    int i = idx >> 6, r = idx & 63;          // M0[i*64+r] = M[r][i]
    Xa[r * 68 + i] = M0[idx];
  }
  __syncthreads();

  float lsc = 0.f;
  float* Xcur = Xa;
  float* Xnxt = Xb;

  for (int m = 1; m < 8; ++m) {
    const float* Mc = Mout + (size_t)(8 * g + m) * 4096;
    float acc[16];
#pragma unroll
    for (int i = 0; i < 16; ++i) acc[i] = 0.f;

    for (int k = 0; k < 64; ++k) {
      float mv = Mc[k * 64 + j];                       // M_m[j][k], coalesced
      const float* xr = Xcur + k * 68 + (w << 4);      // wave-uniform broadcast
      float4 x0 = *(const float4*)(xr + 0);
      float4 x1 = *(const float4*)(xr + 4);
      float4 x2 = *(const float4*)(xr + 8);
      float4 x3 = *(const float4*)(xr + 12);
      acc[0]  = fmaf(mv, x0.x, acc[0]);  acc[1]  = fmaf(mv, x0.y, acc[1]);
      acc[2]  = fmaf(mv, x0.z, acc[2]);  acc[3]  = fmaf(mv, x0.w, acc[3]);
      acc[4]  = fmaf(mv, x1.x, acc[4]);  acc[5]  = fmaf(mv, x1.y, acc[5]);
      acc[6]  = fmaf(mv, x1.z, acc[6]);  acc[7]  = fmaf(mv, x1.w, acc[7]);
      acc[8]  = fmaf(mv, x2.x, acc[8]);  acc[9]  = fmaf(mv, x2.y, acc[9]);
      acc[10] = fmaf(mv, x2.z, acc[10]); acc[11] = fmaf(mv, x2.w, acc[11]);
      acc[12] = fmaf(mv, x3.x, acc[12]); acc[13] = fmaf(mv, x3.y, acc[13]);
      acc[14] = fmaf(mv, x3.z, acc[14]); acc[15] = fmaf(mv, x3.w, acc[15]);
    }

    // block-wide max (entries all > 0)
    float lm = acc[0];
#pragma unroll
    for (int i = 1; i < 16; ++i) lm = fmaxf(lm, acc[i]);
#pragma unroll
    for (int d = 1; d < 64; d <<= 1) lm = fmaxf(lm, __shfl_xor(lm, d));
    if ((tid & 63) == 0) red[w] = lm;
    __syncthreads();
    float bm = fmaxf(fmaxf(red[0], red[1]), fmaxf(red[2], red[3]));
    float inv = 1.f / bm;
    lsc += __logf(bm);
#pragma unroll
    for (int i = 0; i < 16; ++i)
      Xnxt[j * 68 + (w << 4) + i] = acc[i] * inv;
    __syncthreads();
    float* t = Xcur; Xcur = Xnxt; Xnxt = t;
  }

  // store G: Gout[g][i][r] = G[r][i]
  float* out = Gout + (size_t)g * 4096;
  for (int idx = tid; idx < 4096; idx += 256) {
    int i = idx >> 6, r = idx & 63;
    out[idx] = Xcur[r * 68 + i];
  }
  if (tid == 0) {
    float s = lsc;
#pragma unroll
    for (int m = 0; m < 8; ++m) s += lscale[8 * g + m];
    glsc[g] = s;
  }
}

// ---------------- level-2 combine: 16 sequential mat-vecs ----------------
__global__ __launch_bounds__(256) void final_combine(
    const float* __restrict__ Gout, const float* __restrict__ glsc,
    const float* __restrict__ pe, const float* __restrict__ ps,
    const float* __restrict__ pb, float* __restrict__ out) {
  const int tid = threadIdx.x;
  const int j = tid & 63, w = tid >> 6;
  __shared__ float vsh[64];
  __shared__ float part[4 * 64];
  if (tid < 64) vsh[tid] = ps[tid] * pe[tid];   // f0
  __syncthreads();
  double lsc = 0.0;
  for (int gph = 0; gph < 16; ++gph) {
    const float* Gc = Gout + (size_t)gph * 4096;
    const int k0 = w << 4;
    float a0 = 0.f, a1 = 0.f, a2 = 0.f, a3 = 0.f;
#pragma unroll
    for (int kk = 0; kk < 16; kk += 4) {
      a0 = fmaf(vsh[k0 + kk + 0], Gc[(k0 + kk + 0) * 64 + j], a0);
      a1 = fmaf(vsh[k0 + kk + 1], Gc[(k0 + kk + 1) * 64 + j], a1);
      a2 = fmaf(vsh[k0 + kk + 2], Gc[(k0 + kk + 2) * 64 + j], a2);
      a3 = fmaf(vsh[k0 + kk + 3], Gc[(k0 + kk + 3) * 64 + j], a3);
    }
    part[w * 64 + j] = (a0 + a1) + (a2 + a3);
    __syncthreads();
    if (w == 0) {
      float u = part[j] + part[64 + j] + part[128 + j] + part[192 + j];
      float mx = u;
#pragma unroll
      for (int d = 1; d < 64; d <<= 1) mx = fmaxf(mx, __shfl_xor(mx, d));
      vsh[j] = u / mx;
      lsc += (double)__logf(mx) + (double)glsc[gph];
    }
    __syncthreads();
  }
  if (w == 0) {
    float z = vsh[j] * pb[T_LEN * 64 + j];
#pragma unroll
    for (int d = 1; d < 64; d <<= 1) z += __shfl_xor(z, d);
    if (j == 0) out[0] = (float)(-((double)logf(z) + lsc));
  }
}

extern "C" void kernel_launch(void* const* d_in, const int* in_sizes, int n_in,
                              void* d_out, int out_size, void* d_ws, size_t ws_size,
                              hipStream_t stream) {
  const float* s_i      = (const float*)d_in[0];
  const float* W_action = (const float*)d_in[1];
  const float* W_stop   = (const float*)d_in[2];
  const float* W_start  = (const float*)d_in[3];
  const int*   actions  = (const int*)d_in[4];

  char* ws = (char*)d_ws;
  u16*   s_bf  = (u16*)(ws + WS_SBF);
  u16*   wa_t  = (u16*)(ws + WS_WAT);
  u16*   wsm_t = (u16*)(ws + WS_WSMT);
  float* pe    = (float*)(ws + WS_PE);
  float* ps    = (float*)(ws + WS_PS);
  float* pb    = (float*)(ws + WS_PB);
  float* pc    = (float*)(ws + WS_PC);
  float* Mout  = (float*)(ws + WS_MOUT);
  float* lsc   = (float*)(ws + WS_LSC);
  float* Gout  = (float*)(ws + WS_GOUT);
  float* glsc  = (float*)(ws + WS_GLSC);

  conv_s<<<8256, 256, 0, stream>>>(s_i, s_bf);
  conv_wa<<<4096, 256, 0, stream>>>(W_action, wa_t);
  conv_wsm<<<192, 256, 0, stream>>>(W_stop, W_start, wsm_t);
  small_gemm<<<129, 256, 0, stream>>>(s_bf, wsm_t, ps, pb, pc);
  act_gemm<<<dim3(64, 128), 256, 0, stream>>>(s_bf, wa_t, actions, pe);
  chunk_kernel<<<128, 64, 0, stream>>>(pe, ps, pb, pc, Mout, lsc);
  group_combine<<<16, 256, 0, stream>>>(Mout, lsc, Gout, glsc);
  final_combine<<<1, 256, 0, stream>>>(Gout, glsc, pe, ps, pb, (float*)d_out);
}

// Round 7
// 216.411 us; speedup vs baseline: 1.9727x; 1.3888x over previous
//
#include <hip/hip_runtime.h>
#include <stdint.h>

// HMM trajectory-net forward:  -logsumexp over an 8191-step 64-state HMM scan.
// Pipeline:
//   conv_*       : fp32 -> bf16 repacks
//   small_gemm   : start/stop logits via MFMA, fused softmax/sigmoid -> ps, pb, pc
//   act_gemm     : action logits via MFMA, fused row-logsumexp + action-select -> pe
//   chunk_kernel : 128 chunks x 64 steps; 4 waves/chunk, 64x64 transfer matrix in
//                  registers (16 rows/thread); scalars staged in LDS, read as
//                  wave-uniform float4 broadcasts; 1 barrier/step for rank-1 term
//   group_combine: 16 blocks, each folds 8 chunk matrices via fp32 matmul chain (parallel)
//   final_combine: 16 sequential mat-vecs (4-wave split) + boundary terms -> scalar

typedef short bf16x8 __attribute__((ext_vector_type(8)));
typedef float f32x4  __attribute__((ext_vector_type(4)));
typedef unsigned short u16;

#define T_LEN 8192
#define SDIM  256

// ---- workspace layout (bytes) ----
#define WS_SBF    0              // 8256*256 bf16 (padded rows zeroed)
#define WS_WAT    4227072        // 4096*256 bf16  [b*64+n][s]
#define WS_WSMT   6324224        // 192*256 bf16   [col][s]
#define WS_PE     6422528        // 8192*64 f32
#define WS_PS     8519680        // 8193*64 f32
#define WS_PB     10617088       // 8193*64 f32
#define WS_PC     12714496       // 8193*64 f32   (dead after chunk_kernel -> reused for Gout)
#define WS_MOUT   14811904       // 128*4096 f32  [chunk][k][j]
#define WS_LSC    16909056       // 128 f32
#define WS_GOUT   WS_PC                      // 16*4096 f32 (reuses pc region)
#define WS_GLSC   (WS_PC + 262144)           // 16 f32

__device__ inline u16 f2bf(float f) {
  union { float f; uint32_t u; } v; v.f = f;
  uint32_t u = v.u;
  return (u16)((u + 0x7fffu + ((u >> 16) & 1u)) >> 16);
}

// ---------------- converts ----------------
__global__ void conv_s(const float* __restrict__ s_i, u16* __restrict__ s_bf) {
  int idx = blockIdx.x * 256 + threadIdx.x;
  int t = idx >> 8;
  float v = (t < T_LEN + 1) ? s_i[idx] : 0.f;
  s_bf[idx] = f2bf(v);
}

__global__ void conv_wa(const float* __restrict__ Wa, u16* __restrict__ wa_t) {
  int idx = blockIdx.x * 256 + threadIdx.x;
  int s = idx >> 12, bn = idx & 4095;
  wa_t[bn * 256 + s] = f2bf(Wa[idx]);
}

__global__ void conv_wsm(const float* __restrict__ Wstop, const float* __restrict__ Wstart,
                         u16* __restrict__ wsm_t) {
  int idx = blockIdx.x * 256 + threadIdx.x;
  int col = idx >> 8, s = idx & 255;
  float v;
  if (col < 64)       v = Wstart[s * 64 + col];
  else if (col < 128) v = Wstop[s * 128 + (col - 64) * 2 + 0];
  else                v = Wstop[s * 128 + (col - 128) * 2 + 1];
  wsm_t[col * 256 + s] = f2bf(v);
}

// ---------------- action GEMM + fused emit ----------------
__global__ __launch_bounds__(256) void act_gemm(
    const u16* __restrict__ s_bf, const u16* __restrict__ wa_t,
    const int* __restrict__ actions, float* __restrict__ pe) {
  __shared__ uint4 ldsA[64 * 32];
  __shared__ uint4 ldsB[64 * 32];
  const int b  = blockIdx.x;
  const int t0 = blockIdx.y * 64;
  const int tid = threadIdx.x;

  for (int i = tid; i < 64 * 32; i += 256) {
    int row = i >> 5, u = i & 31;
    ldsA[(row * 32 + u) ^ (row & 7)] =
        *(const uint4*)(s_bf + (size_t)(t0 + row) * 256 + u * 8);
    ldsB[(row * 32 + u) ^ (row & 7)] =
        *(const uint4*)(wa_t + (size_t)(b * 64 + row) * 256 + u * 8);
  }
  __syncthreads();

  const int lane = tid & 63, w = tid >> 6;
  const int g = lane >> 4, c = lane & 15;
  f32x4 acc[4];
#pragma unroll
  for (int i = 0; i < 4; ++i) acc[i] = (f32x4){0.f, 0.f, 0.f, 0.f};

#pragma unroll
  for (int kk = 0; kk < 8; ++kk) {
    int u = kk * 4 + g;
    int arow = w * 16 + c;
    bf16x8 af = *(const bf16x8*)&ldsA[(arow * 32 + u) ^ (arow & 7)];
#pragma unroll
    for (int cf = 0; cf < 4; ++cf) {
      int brow = cf * 16 + c;
      bf16x8 bfr = *(const bf16x8*)&ldsB[(brow * 32 + u) ^ (brow & 7)];
      acc[cf] = __builtin_amdgcn_mfma_f32_16x16x32_bf16(af, bfr, acc[cf], 0, 0, 0);
    }
  }

#pragma unroll
  for (int q = 0; q < 4; ++q) {
    float v0 = acc[0][q], v1 = acc[1][q], v2 = acc[2][q], v3 = acc[3][q];
    float m = fmaxf(fmaxf(v0, v1), fmaxf(v2, v3));
#pragma unroll
    for (int d = 1; d < 16; d <<= 1) m = fmaxf(m, __shfl_xor(m, d));
    float s = __expf(v0 - m) + __expf(v1 - m) + __expf(v2 - m) + __expf(v3 - m);
#pragma unroll
    for (int d = 1; d < 16; d <<= 1) s += __shfl_xor(s, d);
    float lse = m + __logf(s);
    int t = t0 + w * 16 + g * 4 + q;
    int a = actions[t];
    int acf = a >> 4;
    float vsel = (acf == 0) ? v0 : (acf == 1) ? v1 : (acf == 2) ? v2 : v3;
    if (c == (a & 15)) pe[t * 64 + b] = __expf(vsel - lse);
  }
}

// ---------------- start/stop GEMM + fused softmax/sigmoid ----------------
__global__ __launch_bounds__(256) void small_gemm(
    const u16* __restrict__ s_bf, const u16* __restrict__ wsm_t,
    float* __restrict__ ps, float* __restrict__ pb, float* __restrict__ pc) {
  __shared__ uint4 ldsA[64 * 16];
  __shared__ uint4 ldsB[192 * 16];
  const int t0 = blockIdx.x * 64;
  const int tid = threadIdx.x;
  const int lane = tid & 63, w = tid >> 6;
  const int g = lane >> 4, c = lane & 15;

  f32x4 acc[12];
#pragma unroll
  for (int i = 0; i < 12; ++i) acc[i] = (f32x4){0.f, 0.f, 0.f, 0.f};

  for (int kh = 0; kh < 2; ++kh) {
    if (kh) __syncthreads();
    for (int i = tid; i < 64 * 16; i += 256) {
      int row = i >> 4, u = i & 15;
      ldsA[(row * 16 + u) ^ (row & 7)] =
          *(const uint4*)(s_bf + (size_t)(t0 + row) * 256 + kh * 128 + u * 8);
    }
    for (int i = tid; i < 192 * 16; i += 256) {
      int row = i >> 4, u = i & 15;
      ldsB[(row * 16 + u) ^ (row & 7)] =
          *(const uint4*)(wsm_t + (size_t)row * 256 + kh * 128 + u * 8);
    }
    __syncthreads();
#pragma unroll
    for (int kk = 0; kk < 4; ++kk) {
      int u = kk * 4 + g;
      int arow = w * 16 + c;
      bf16x8 af = *(const bf16x8*)&ldsA[(arow * 16 + u) ^ (arow & 7)];
#pragma unroll
      for (int cf = 0; cf < 12; ++cf) {
        int brow = cf * 16 + c;
        bf16x8 bfr = *(const bf16x8*)&ldsB[(brow * 16 + u) ^ (brow & 7)];
        acc[cf] = __builtin_amdgcn_mfma_f32_16x16x32_bf16(af, bfr, acc[cf], 0, 0, 0);
      }
    }
  }

#pragma unroll
  for (int q = 0; q < 4; ++q) {
    int t = t0 + w * 16 + g * 4 + q;
    float v0 = acc[0][q], v1 = acc[1][q], v2 = acc[2][q], v3 = acc[3][q];
    float m = fmaxf(fmaxf(v0, v1), fmaxf(v2, v3));
#pragma unroll
    for (int d = 1; d < 16; d <<= 1) m = fmaxf(m, __shfl_xor(m, d));
    float s = __expf(v0 - m) + __expf(v1 - m) + __expf(v2 - m) + __expf(v3 - m);
#pragma unroll
    for (int d = 1; d < 16; d <<= 1) s += __shfl_xor(s, d);
    float lse = m + __logf(s);
    if (t <= T_LEN) {
      ps[t * 64 + 0 * 16 + c] = __expf(v0 - lse);
      ps[t * 64 + 1 * 16 + c] = __expf(v1 - lse);
      ps[t * 64 + 2 * 16 + c] = __expf(v2 - lse);
      ps[t * 64 + 3 * 16 + c] = __expf(v3 - lse);
#pragma unroll
      for (int bf = 0; bf < 4; ++bf) {
        float l0 = acc[4 + bf][q], l1 = acc[8 + bf][q];
        float d01 = l0 - l1;
        pb[t * 64 + bf * 16 + c] = 1.f / (1.f + __expf(-d01));
        pc[t * 64 + bf * 16 + c] = 1.f / (1.f + __expf(d01));
      }
    }
  }
}

// ---------------- chunked scan: 4 waves per chunk ----------------
// Thread (w, lane) holds M[w*16+jj][lane], jj=0..15.  Step: M <- A_t M,
// A_t = diag(e)(s b^T + diag(c)):  wv[k] = sum_j b_j M[j][k];
// M'[j][k] = ec_j M[j][k] + es_j wv[k].
// Scalars (b, ec, es) staged in LDS; read as wave-uniform float4 broadcasts.
// Rank-1 term: per-wave partials through double-buffered LDS, 1 barrier/step.
// Last chunk pads to 64 steps with identity (ec=1, es=0, b=0).
__global__ __launch_bounds__(256) void chunk_kernel(
    const float* __restrict__ pe, const float* __restrict__ ps,
    const float* __restrict__ pb, const float* __restrict__ pc,
    float* __restrict__ Mout, float* __restrict__ lscale) {
  __shared__ float scal[64 * 192];   // per step: [b(64) | ec(64) | es(64)]
  __shared__ float part[2][256];
  __shared__ float mxs[4];
  const int ck = blockIdx.x;
  const int tid = threadIdx.x;
  const int lane = tid & 63;
  const int w = tid >> 6;
  const int tlo = ck * 64 + 1;

  // stage chunk scalars into LDS (coalesced global reads)
#pragma unroll
  for (int it = 0; it < 16; ++it) {
    int i = tid + 256 * it;            // [0, 4096)
    int st = i >> 6, j = i & 63;
    int t = tlo + st;
    if (t <= T_LEN - 1) {
      int base = t * 64 + j;
      float b = pb[base], e = pe[base], s = ps[base], c = pc[base];
      scal[st * 192 + j]       = b;
      scal[st * 192 + 64 + j]  = e * c;
      scal[st * 192 + 128 + j] = e * s;
    } else {
      scal[st * 192 + j]       = 0.f;
      scal[st * 192 + 64 + j]  = 1.f;
      scal[st * 192 + 128 + j] = 0.f;
    }
  }
  __syncthreads();

  float M[16];
#pragma unroll
  for (int jj = 0; jj < 16; ++jj) M[jj] = ((w * 16 + jj) == lane) ? 1.f : 0.f;
  float lsc = 0.f;
  int pbuf = 0;

  for (int st = 0; st < 64; ++st) {
    const float* sb = &scal[st * 192];
    // per-wave partial of wv
    float p0 = 0.f, p1 = 0.f, p2 = 0.f, p3 = 0.f;
#pragma unroll
    for (int q = 0; q < 4; ++q) {
      float4 bq = *(const float4*)(sb + w * 16 + q * 4);   // uniform broadcast
      p0 = fmaf(bq.x, M[q * 4 + 0], p0);
      p1 = fmaf(bq.y, M[q * 4 + 1], p1);
      p2 = fmaf(bq.z, M[q * 4 + 2], p2);
      p3 = fmaf(bq.w, M[q * 4 + 3], p3);
    }
    part[pbuf][w * 64 + lane] = (p0 + p1) + (p2 + p3);
    __syncthreads();
    float wv = part[pbuf][lane] + part[pbuf][64 + lane] +
               part[pbuf][128 + lane] + part[pbuf][192 + lane];
    pbuf ^= 1;
    // update
#pragma unroll
    for (int q = 0; q < 4; ++q) {
      float4 ecq = *(const float4*)(sb + 64 + w * 16 + q * 4);
      float4 esq = *(const float4*)(sb + 128 + w * 16 + q * 4);
      M[q * 4 + 0] = fmaf(ecq.x, M[q * 4 + 0], esq.x * wv);
      M[q * 4 + 1] = fmaf(ecq.y, M[q * 4 + 1], esq.y * wv);
      M[q * 4 + 2] = fmaf(ecq.z, M[q * 4 + 2], esq.z * wv);
      M[q * 4 + 3] = fmaf(ecq.w, M[q * 4 + 3], esq.w * wv);
    }
    if ((st & 7) == 7) {
      float mx = M[0];
#pragma unroll
      for (int jj = 1; jj < 16; ++jj) mx = fmaxf(mx, M[jj]);
#pragma unroll
      for (int d = 1; d < 64; d <<= 1) mx = fmaxf(mx, __shfl_xor(mx, d));
      if (lane == 0) mxs[w] = mx;
      __syncthreads();
      float bm = fmaxf(fmaxf(mxs[0], mxs[1]), fmaxf(mxs[2], mxs[3]));
      float inv = 1.f / bm;
#pragma unroll
      for (int jj = 0; jj < 16; ++jj) M[jj] *= inv;
      lsc += __logf(bm);   // every thread tracks; only tid 0 writes
    }
  }

  // store: Mout[ck][i][j] = M[j][i];  i = lane, j = w*16 + jj  (16B stores)
  float* out = Mout + (size_t)ck * 4096;
#pragma unroll
  for (int q = 0; q < 4; ++q) {
    float4 v = make_float4(M[q * 4 + 0], M[q * 4 + 1], M[q * 4 + 2], M[q * 4 + 3]);
    *(float4*)(out + lane * 64 + w * 16 + q * 4) = v;
  }
  if (tid == 0) lscale[ck] = lsc;
}

// ---------------- level-1 combine: 16 groups x 8 chunk matrices ----------------
// Mout[ck][i][j] = M_ck[j][i].  Block g computes G = M_{8g+7} * ... * M_{8g},
// renormalizing (max->1) after each multiply.  Gout same layout as Mout.
__global__ __launch_bounds__(256) void group_combine(
    const float* __restrict__ Mout, const float* __restrict__ lscale,
    float* __restrict__ Gout, float* __restrict__ glsc) {
  const int g = blockIdx.x;
  const int tid = threadIdx.x;
  const int j = tid & 63;        // output row
  const int w = tid >> 6;        // wave -> column group [w*16, w*16+16)
  __shared__ float Xa[64 * 68];  // X[r][c] at Xa[r*68+c]; stride 68 keeps float4 alignment
  __shared__ float Xb[64 * 68];
  __shared__ float red[4];

  const float* M0 = Mout + (size_t)(8 * g) * 4096;
  for (int idx = tid; idx < 4096; idx += 256) {
    int i = idx >> 6, r = idx & 63;          // M0[i*64+r] = M[r][i]
    Xa[r * 68 + i] = M0[idx];
  }
  __syncthreads();

  float lsc = 0.f;
  float* Xcur = Xa;
  float* Xnxt = Xb;

  for (int m = 1; m < 8; ++m) {
    const float* Mc = Mout + (size_t)(8 * g + m) * 4096;
    float acc[16];
#pragma unroll
    for (int i = 0; i < 16; ++i) acc[i] = 0.f;

    for (int k = 0; k < 64; ++k) {
      float mv = Mc[k * 64 + j];                       // M_m[j][k], coalesced
      const float* xr = Xcur + k * 68 + (w << 4);      // wave-uniform broadcast
      float4 x0 = *(const float4*)(xr + 0);
      float4 x1 = *(const float4*)(xr + 4);
      float4 x2 = *(const float4*)(xr + 8);
      float4 x3 = *(const float4*)(xr + 12);
      acc[0]  = fmaf(mv, x0.x, acc[0]);  acc[1]  = fmaf(mv, x0.y, acc[1]);
      acc[2]  = fmaf(mv, x0.z, acc[2]);  acc[3]  = fmaf(mv, x0.w, acc[3]);
      acc[4]  = fmaf(mv, x1.x, acc[4]);  acc[5]  = fmaf(mv, x1.y, acc[5]);
      acc[6]  = fmaf(mv, x1.z, acc[6]);  acc[7]  = fmaf(mv, x1.w, acc[7]);
      acc[8]  = fmaf(mv, x2.x, acc[8]);  acc[9]  = fmaf(mv, x2.y, acc[9]);
      acc[10] = fmaf(mv, x2.z, acc[10]); acc[11] = fmaf(mv, x2.w, acc[11]);
      acc[12] = fmaf(mv, x3.x, acc[12]); acc[13] = fmaf(mv, x3.y, acc[13]);
      acc[14] = fmaf(mv, x3.z, acc[14]); acc[15] = fmaf(mv, x3.w, acc[15]);
    }

    // block-wide max (entries all > 0)
    float lm = acc[0];
#pragma unroll
    for (int i = 1; i < 16; ++i) lm = fmaxf(lm, acc[i]);
#pragma unroll
    for (int d = 1; d < 64; d <<= 1) lm = fmaxf(lm, __shfl_xor(lm, d));
    if ((tid & 63) == 0) red[w] = lm;
    __syncthreads();
    float bm = fmaxf(fmaxf(red[0], red[1]), fmaxf(red[2], red[3]));
    float inv = 1.f / bm;
    lsc += __logf(bm);
#pragma unroll
    for (int i = 0; i < 16; ++i)
      Xnxt[j * 68 + (w << 4) + i] = acc[i] * inv;
    __syncthreads();
    float* t = Xcur; Xcur = Xnxt; Xnxt = t;
  }

  // store G: Gout[g][i][r] = G[r][i]
  float* out = Gout + (size_t)g * 4096;
  for (int idx = tid; idx < 4096; idx += 256) {
    int i = idx >> 6, r = idx & 63;
    out[idx] = Xcur[r * 68 + i];
  }
  if (tid == 0) {
    float s = lsc;
#pragma unroll
    for (int m = 0; m < 8; ++m) s += lscale[8 * g + m];
    glsc[g] = s;
  }
}

// ---------------- level-2 combine: 16 sequential mat-vecs ----------------
__global__ __launch_bounds__(256) void final_combine(
    const float* __restrict__ Gout, const float* __restrict__ glsc,
    const float* __restrict__ pe, const float* __restrict__ ps,
    const float* __restrict__ pb, float* __restrict__ out) {
  const int tid = threadIdx.x;
  const int j = tid & 63, w = tid >> 6;
  __shared__ float vsh[64];
  __shared__ float part[4 * 64];
  if (tid < 64) vsh[tid] = ps[tid] * pe[tid];   // f0
  __syncthreads();
  double lsc = 0.0;
  for (int gph = 0; gph < 16; ++gph) {
    const float* Gc = Gout + (size_t)gph * 4096;
    const int k0 = w << 4;
    float a0 = 0.f, a1 = 0.f, a2 = 0.f, a3 = 0.f;
#pragma unroll
    for (int kk = 0; kk < 16; kk += 4) {
      a0 = fmaf(vsh[k0 + kk + 0], Gc[(k0 + kk + 0) * 64 + j], a0);
      a1 = fmaf(vsh[k0 + kk + 1], Gc[(k0 + kk + 1) * 64 + j], a1);
      a2 = fmaf(vsh[k0 + kk + 2], Gc[(k0 + kk + 2) * 64 + j], a2);
      a3 = fmaf(vsh[k0 + kk + 3], Gc[(k0 + kk + 3) * 64 + j], a3);
    }
    part[w * 64 + j] = (a0 + a1) + (a2 + a3);
    __syncthreads();
    if (w == 0) {
      float u = part[j] + part[64 + j] + part[128 + j] + part[192 + j];
      float mx = u;
#pragma unroll
      for (int d = 1; d < 64; d <<= 1) mx = fmaxf(mx, __shfl_xor(mx, d));
      vsh[j] = u / mx;
      lsc += (double)__logf(mx) + (double)glsc[gph];
    }
    __syncthreads();
  }
  if (w == 0) {
    float z = vsh[j] * pb[T_LEN * 64 + j];
#pragma unroll
    for (int d = 1; d < 64; d <<= 1) z += __shfl_xor(z, d);
    if (j == 0) out[0] = (float)(-((double)logf(z) + lsc));
  }
}

extern "C" void kernel_launch(void* const* d_in, const int* in_sizes, int n_in,
                              void* d_out, int out_size, void* d_ws, size_t ws_size,
                              hipStream_t stream) {
  const float* s_i      = (const float*)d_in[0];
  const float* W_action = (const float*)d_in[1];
  const float* W_stop   = (const float*)d_in[2];
  const float* W_start  = (const float*)d_in[3];
  const int*   actions  = (const int*)d_in[4];

  char* ws = (char*)d_ws;
  u16*   s_bf  = (u16*)(ws + WS_SBF);
  u16*   wa_t  = (u16*)(ws + WS_WAT);
  u16*   wsm_t = (u16*)(ws + WS_WSMT);
  float* pe    = (float*)(ws + WS_PE);
  float* ps    = (float*)(ws + WS_PS);
  float* pb    = (float*)(ws + WS_PB);
  float* pc    = (float*)(ws + WS_PC);
  float* Mout  = (float*)(ws + WS_MOUT);
  float* lsc   = (float*)(ws + WS_LSC);
  float* Gout  = (float*)(ws + WS_GOUT);
  float* glsc  = (float*)(ws + WS_GLSC);

  conv_s<<<8256, 256, 0, stream>>>(s_i, s_bf);
  conv_wa<<<4096, 256, 0, stream>>>(W_action, wa_t);
  conv_wsm<<<192, 256, 0, stream>>>(W_stop, W_start, wsm_t);
  small_gemm<<<129, 256, 0, stream>>>(s_bf, wsm_t, ps, pb, pc);
  act_gemm<<<dim3(64, 128), 256, 0, stream>>>(s_bf, wa_t, actions, pe);
  chunk_kernel<<<128, 256, 0, stream>>>(pe, ps, pb, pc, Mout, lsc);
  group_combine<<<16, 256, 0, stream>>>(Mout, lsc, Gout, glsc);
  final_combine<<<1, 256, 0, stream>>>(Gout, glsc, pe, ps, pb, (float*)d_out);
}

// Round 8
// 193.595 us; speedup vs baseline: 2.2052x; 1.1179x over previous
//
#include <hip/hip_runtime.h>
#include <stdint.h>

// HMM trajectory-net forward:  -logsumexp over an 8191-step 64-state HMM scan.
// Pipeline:
//   conv_*       : fp32 -> bf16 repacks
//   small_gemm   : start/stop logits via MFMA, fused softmax/sigmoid -> ps, pb, pc
//   act_gemm     : 128x128xBK64 double-buffered MFMA GEMM + fused row-logsumexp
//                  + action-select -> pe   (8 waves, 2 blocks/CU, XOR-swizzled LDS)
//   chunk_kernel : 128 chunks x 64 steps; 4 waves/chunk, 64x64 transfer matrix in
//                  registers; scalars staged in LDS
//   group_combine: 16 blocks, each folds 8 chunk matrices via fp32 matmul chain
//   final_combine: 16 sequential mat-vecs (4-wave split) + boundary terms -> scalar

typedef short bf16x8 __attribute__((ext_vector_type(8)));
typedef float f32x4  __attribute__((ext_vector_type(4)));
typedef unsigned short u16;

#define T_LEN 8192
#define SDIM  256

// ---- workspace layout (bytes) ----
#define WS_SBF    0              // 8256*256 bf16 (padded rows zeroed)
#define WS_WAT    4227072        // 4096*256 bf16  [b*64+n][s]
#define WS_WSMT   6324224        // 192*256 bf16   [col][s]
#define WS_PE     6422528        // 8192*64 f32
#define WS_PS     8519680        // 8193*64 f32
#define WS_PB     10617088       // 8193*64 f32
#define WS_PC     12714496       // 8193*64 f32   (dead after chunk_kernel -> reused for Gout)
#define WS_MOUT   14811904       // 128*4096 f32  [chunk][k][j]
#define WS_LSC    16909056       // 128 f32
#define WS_GOUT   WS_PC                      // 16*4096 f32 (reuses pc region)
#define WS_GLSC   (WS_PC + 262144)           // 16 f32

__device__ inline u16 f2bf(float f) {
  union { float f; uint32_t u; } v; v.f = f;
  uint32_t u = v.u;
  return (u16)((u + 0x7fffu + ((u >> 16) & 1u)) >> 16);
}

// ---------------- converts ----------------
__global__ void conv_s(const float* __restrict__ s_i, u16* __restrict__ s_bf) {
  int idx = blockIdx.x * 256 + threadIdx.x;
  int t = idx >> 8;
  float v = (t < T_LEN + 1) ? s_i[idx] : 0.f;
  s_bf[idx] = f2bf(v);
}

__global__ void conv_wa(const float* __restrict__ Wa, u16* __restrict__ wa_t) {
  int idx = blockIdx.x * 256 + threadIdx.x;
  int s = idx >> 12, bn = idx & 4095;
  wa_t[bn * 256 + s] = f2bf(Wa[idx]);
}

__global__ void conv_wsm(const float* __restrict__ Wstop, const float* __restrict__ Wstart,
                         u16* __restrict__ wsm_t) {
  int idx = blockIdx.x * 256 + threadIdx.x;
  int col = idx >> 8, s = idx & 255;
  float v;
  if (col < 64)       v = Wstart[s * 64 + col];
  else if (col < 128) v = Wstop[s * 128 + (col - 64) * 2 + 0];
  else                v = Wstop[s * 128 + (col - 128) * 2 + 1];
  wsm_t[col * 256 + s] = f2bf(v);
}

// ---------------- action GEMM + fused emit ----------------
// 128(t) x 128(bn) x K256 in BK=64 steps, double-buffered LDS.
// 8 waves: wm=wave>>1 (4), wn=wave&1 (2).  Wave owns 32 t-rows x 64 bn-cols
// (= one full b-group -> softmax stays wave-local).
// LDS tile layout: [row][slot] of uint4 (8 bf16), slot stored at (slot ^ (row&7)).
__global__ __launch_bounds__(512, 4) void act_gemm(
    const u16* __restrict__ s_bf, const u16* __restrict__ wa_t,
    const int* __restrict__ actions, float* __restrict__ pe) {
  __shared__ uint4 ldsA[2][128 * 8];
  __shared__ uint4 ldsB[2][128 * 8];
  const int tid = threadIdx.x;
  const int lane = tid & 63;
  const int wv = tid >> 6;
  const int wm = wv >> 1, wn = wv & 1;
  const int g = lane >> 4, c = lane & 15;

  // XCD-bijective swizzle over 2048 blocks (2048 % 8 == 0)
  int bid = blockIdx.y * 32 + blockIdx.x;
  int swz = (bid & 7) * 256 + (bid >> 3);
  const int t0 = (swz >> 5) * 128;         // m-tile (64 tiles)
  const int n0 = (swz & 31) * 128;         // n-tile (32 tiles)

  // staging map: pass ii in {0,1}: i = tid + 512*ii; r = i>>3 (0..127), u = i&7
  const int sr0 = tid >> 3, su = tid & 7;

  uint4 ra[2], rb[2];
  auto issue_loads = [&](int bk) {
#pragma unroll
    for (int ii = 0; ii < 2; ++ii) {
      int r = sr0 + 64 * ii;
      int uu = (su ^ (r & 7));
      ra[ii] = *(const uint4*)(s_bf + (size_t)(t0 + r) * 256 + bk * 64 + uu * 8);
      rb[ii] = *(const uint4*)(wa_t + (size_t)(n0 + r) * 256 + bk * 64 + uu * 8);
    }
  };
  auto write_lds = [&](int buf) {
#pragma unroll
    for (int ii = 0; ii < 2; ++ii) {
      int r = sr0 + 64 * ii;
      ldsA[buf][r * 8 + su] = ra[ii];
      ldsB[buf][r * 8 + su] = rb[ii];
    }
  };

  f32x4 acc[2][4];
#pragma unroll
  for (int mf = 0; mf < 2; ++mf)
#pragma unroll
    for (int nf = 0; nf < 4; ++nf) acc[mf][nf] = (f32x4){0.f, 0.f, 0.f, 0.f};

  issue_loads(0);
  write_lds(0);
  __syncthreads();

  int buf = 0;
#pragma unroll
  for (int bk = 0; bk < 4; ++bk) {
    if (bk < 3) issue_loads(bk + 1);
#pragma unroll
    for (int ks = 0; ks < 2; ++ks) {
      bf16x8 af[2];
#pragma unroll
      for (int mf = 0; mf < 2; ++mf) {
        int rr = wm * 32 + mf * 16 + c;
        af[mf] = *(const bf16x8*)&ldsA[buf][rr * 8 + ((ks * 4 + g) ^ (rr & 7))];
      }
#pragma unroll
      for (int nf = 0; nf < 4; ++nf) {
        int rr = wn * 64 + nf * 16 + c;
        bf16x8 bfv = *(const bf16x8*)&ldsB[buf][rr * 8 + ((ks * 4 + g) ^ (rr & 7))];
#pragma unroll
        for (int mf = 0; mf < 2; ++mf)
          acc[mf][nf] = __builtin_amdgcn_mfma_f32_16x16x32_bf16(af[mf], bfv, acc[mf][nf], 0, 0, 0);
      }
    }
    if (bk < 3) {
      write_lds(buf ^ 1);
      __syncthreads();
    }
    buf ^= 1;
  }

  // epilogue: per m-frag, per q-row: logsumexp over the wave's 64 cols (one b-group)
  const int b0 = (n0 >> 6) + wn;
#pragma unroll
  for (int mf = 0; mf < 2; ++mf) {
#pragma unroll
    for (int q = 0; q < 4; ++q) {
      float v0 = acc[mf][0][q], v1 = acc[mf][1][q], v2 = acc[mf][2][q], v3 = acc[mf][3][q];
      float m = fmaxf(fmaxf(v0, v1), fmaxf(v2, v3));
#pragma unroll
      for (int d = 1; d < 16; d <<= 1) m = fmaxf(m, __shfl_xor(m, d));
      float s = __expf(v0 - m) + __expf(v1 - m) + __expf(v2 - m) + __expf(v3 - m);
#pragma unroll
      for (int d = 1; d < 16; d <<= 1) s += __shfl_xor(s, d);
      float lse = m + __logf(s);
      int t = t0 + wm * 32 + mf * 16 + g * 4 + q;
      int a = actions[t];
      int acf = a >> 4;
      float vsel = (acf == 0) ? v0 : (acf == 1) ? v1 : (acf == 2) ? v2 : v3;
      if (c == (a & 15)) pe[t * 64 + b0] = __expf(vsel - lse);
    }
  }
}

// ---------------- start/stop GEMM + fused softmax/sigmoid ----------------
__global__ __launch_bounds__(256) void small_gemm(
    const u16* __restrict__ s_bf, const u16* __restrict__ wsm_t,
    float* __restrict__ ps, float* __restrict__ pb, float* __restrict__ pc) {
  __shared__ uint4 ldsA[64 * 16];
  __shared__ uint4 ldsB[192 * 16];
  const int t0 = blockIdx.x * 64;
  const int tid = threadIdx.x;
  const int lane = tid & 63, w = tid >> 6;
  const int g = lane >> 4, c = lane & 15;

  f32x4 acc[12];
#pragma unroll
  for (int i = 0; i < 12; ++i) acc[i] = (f32x4){0.f, 0.f, 0.f, 0.f};

  for (int kh = 0; kh < 2; ++kh) {
    if (kh) __syncthreads();
    for (int i = tid; i < 64 * 16; i += 256) {
      int row = i >> 4, u = i & 15;
      ldsA[(row * 16 + u) ^ (row & 7)] =
          *(const uint4*)(s_bf + (size_t)(t0 + row) * 256 + kh * 128 + u * 8);
    }
    for (int i = tid; i < 192 * 16; i += 256) {
      int row = i >> 4, u = i & 15;
      ldsB[(row * 16 + u) ^ (row & 7)] =
          *(const uint4*)(wsm_t + (size_t)row * 256 + kh * 128 + u * 8);
    }
    __syncthreads();
#pragma unroll
    for (int kk = 0; kk < 4; ++kk) {
      int u = kk * 4 + g;
      int arow = w * 16 + c;
      bf16x8 af = *(const bf16x8*)&ldsA[(arow * 16 + u) ^ (arow & 7)];
#pragma unroll
      for (int cf = 0; cf < 12; ++cf) {
        int brow = cf * 16 + c;
        bf16x8 bfr = *(const bf16x8*)&ldsB[(brow * 16 + u) ^ (brow & 7)];
        acc[cf] = __builtin_amdgcn_mfma_f32_16x16x32_bf16(af, bfr, acc[cf], 0, 0, 0);
      }
    }
  }

#pragma unroll
  for (int q = 0; q < 4; ++q) {
    int t = t0 + w * 16 + g * 4 + q;
    float v0 = acc[0][q], v1 = acc[1][q], v2 = acc[2][q], v3 = acc[3][q];
    float m = fmaxf(fmaxf(v0, v1), fmaxf(v2, v3));
#pragma unroll
    for (int d = 1; d < 16; d <<= 1) m = fmaxf(m, __shfl_xor(m, d));
    float s = __expf(v0 - m) + __expf(v1 - m) + __expf(v2 - m) + __expf(v3 - m);
#pragma unroll
    for (int d = 1; d < 16; d <<= 1) s += __shfl_xor(s, d);
    float lse = m + __logf(s);
    if (t <= T_LEN) {
      ps[t * 64 + 0 * 16 + c] = __expf(v0 - lse);
      ps[t * 64 + 1 * 16 + c] = __expf(v1 - lse);
      ps[t * 64 + 2 * 16 + c] = __expf(v2 - lse);
      ps[t * 64 + 3 * 16 + c] = __expf(v3 - lse);
#pragma unroll
      for (int bf = 0; bf < 4; ++bf) {
        float l0 = acc[4 + bf][q], l1 = acc[8 + bf][q];
        float d01 = l0 - l1;
        pb[t * 64 + bf * 16 + c] = 1.f / (1.f + __expf(-d01));
        pc[t * 64 + bf * 16 + c] = 1.f / (1.f + __expf(d01));
      }
    }
  }
}

// ---------------- chunked scan: 4 waves per chunk ----------------
__global__ __launch_bounds__(256) void chunk_kernel(
    const float* __restrict__ pe, const float* __restrict__ ps,
    const float* __restrict__ pb, const float* __restrict__ pc,
    float* __restrict__ Mout, float* __restrict__ lscale) {
  __shared__ float scal[64 * 192];   // per step: [b(64) | ec(64) | es(64)]
  __shared__ float part[2][256];
  __shared__ float mxs[4];
  const int ck = blockIdx.x;
  const int tid = threadIdx.x;
  const int lane = tid & 63;
  const int w = tid >> 6;
  const int tlo = ck * 64 + 1;

#pragma unroll
  for (int it = 0; it < 16; ++it) {
    int i = tid + 256 * it;
    int st = i >> 6, j = i & 63;
    int t = tlo + st;
    if (t <= T_LEN - 1) {
      int base = t * 64 + j;
      float b = pb[base], e = pe[base], s = ps[base], c = pc[base];
      scal[st * 192 + j]       = b;
      scal[st * 192 + 64 + j]  = e * c;
      scal[st * 192 + 128 + j] = e * s;
    } else {
      scal[st * 192 + j]       = 0.f;
      scal[st * 192 + 64 + j]  = 1.f;
      scal[st * 192 + 128 + j] = 0.f;
    }
  }
  __syncthreads();

  float M[16];
#pragma unroll
  for (int jj = 0; jj < 16; ++jj) M[jj] = ((w * 16 + jj) == lane) ? 1.f : 0.f;
  float lsc = 0.f;
  int pbuf = 0;

  for (int st = 0; st < 64; ++st) {
    const float* sb = &scal[st * 192];
    float p0 = 0.f, p1 = 0.f, p2 = 0.f, p3 = 0.f;
#pragma unroll
    for (int q = 0; q < 4; ++q) {
      float4 bq = *(const float4*)(sb + w * 16 + q * 4);
      p0 = fmaf(bq.x, M[q * 4 + 0], p0);
      p1 = fmaf(bq.y, M[q * 4 + 1], p1);
      p2 = fmaf(bq.z, M[q * 4 + 2], p2);
      p3 = fmaf(bq.w, M[q * 4 + 3], p3);
    }
    part[pbuf][w * 64 + lane] = (p0 + p1) + (p2 + p3);
    __syncthreads();
    float wv = part[pbuf][lane] + part[pbuf][64 + lane] +
               part[pbuf][128 + lane] + part[pbuf][192 + lane];
    pbuf ^= 1;
#pragma unroll
    for (int q = 0; q < 4; ++q) {
      float4 ecq = *(const float4*)(sb + 64 + w * 16 + q * 4);
      float4 esq = *(const float4*)(sb + 128 + w * 16 + q * 4);
      M[q * 4 + 0] = fmaf(ecq.x, M[q * 4 + 0], esq.x * wv);
      M[q * 4 + 1] = fmaf(ecq.y, M[q * 4 + 1], esq.y * wv);
      M[q * 4 + 2] = fmaf(ecq.z, M[q * 4 + 2], esq.z * wv);
      M[q * 4 + 3] = fmaf(ecq.w, M[q * 4 + 3], esq.w * wv);
    }
    if ((st & 7) == 7) {
      float mx = M[0];
#pragma unroll
      for (int jj = 1; jj < 16; ++jj) mx = fmaxf(mx, M[jj]);
#pragma unroll
      for (int d = 1; d < 64; d <<= 1) mx = fmaxf(mx, __shfl_xor(mx, d));
      if (lane == 0) mxs[w] = mx;
      __syncthreads();
      float bm = fmaxf(fmaxf(mxs[0], mxs[1]), fmaxf(mxs[2], mxs[3]));
      float inv = 1.f / bm;
#pragma unroll
      for (int jj = 0; jj < 16; ++jj) M[jj] *= inv;
      lsc += __logf(bm);
    }
  }

  float* out = Mout + (size_t)ck * 4096;
#pragma unroll
  for (int q = 0; q < 4; ++q) {
    float4 v = make_float4(M[q * 4 + 0], M[q * 4 + 1], M[q * 4 + 2], M[q * 4 + 3]);
    *(float4*)(out + lane * 64 + w * 16 + q * 4) = v;
  }
  if (tid == 0) lscale[ck] = lsc;
}

// ---------------- level-1 combine: 16 groups x 8 chunk matrices ----------------
__global__ __launch_bounds__(256) void group_combine(
    const float* __restrict__ Mout, const float* __restrict__ lscale,
    float* __restrict__ Gout, float* __restrict__ glsc) {
  const int g = blockIdx.x;
  const int tid = threadIdx.x;
  const int j = tid & 63;
  const int w = tid >> 6;
  __shared__ float Xa[64 * 68];
  __shared__ float Xb[64 * 68];
  __shared__ float red[4];

  const float* M0 = Mout + (size_t)(8 * g) * 4096;
  for (int idx = tid; idx < 4096; idx += 256) {
    int i = idx >> 6, r = idx & 63;
    Xa[r * 68 + i] = M0[idx];
  }
  __syncthreads();

  float lsc = 0.f;
  float* Xcur = Xa;
  float* Xnxt = Xb;

  for (int m = 1; m < 8; ++m) {
    const float* Mc = Mout + (size_t)(8 * g + m) * 4096;
    float acc[16];
#pragma unroll
    for (int i = 0; i < 16; ++i) acc[i] = 0.f;

    for (int k = 0; k < 64; ++k) {
      float mv = Mc[k * 64 + j];
      const float* xr = Xcur + k * 68 + (w << 4);
      float4 x0 = *(const float4*)(xr + 0);
      float4 x1 = *(const float4*)(xr + 4);
      float4 x2 = *(const float4*)(xr + 8);
      float4 x3 = *(const float4*)(xr + 12);
      acc[0]  = fmaf(mv, x0.x, acc[0]);  acc[1]  = fmaf(mv, x0.y, acc[1]);
      acc[2]  = fmaf(mv, x0.z, acc[2]);  acc[3]  = fmaf(mv, x0.w, acc[3]);
      acc[4]  = fmaf(mv, x1.x, acc[4]);  acc[5]  = fmaf(mv, x1.y, acc[5]);
      acc[6]  = fmaf(mv, x1.z, acc[6]);  acc[7]  = fmaf(mv, x1.w, acc[7]);
      acc[8]  = fmaf(mv, x2.x, acc[8]);  acc[9]  = fmaf(mv, x2.y, acc[9]);
      acc[10] = fmaf(mv, x2.z, acc[10]); acc[11] = fmaf(mv, x2.w, acc[11]);
      acc[12] = fmaf(mv, x3.x, acc[12]); acc[13] = fmaf(mv, x3.y, acc[13]);
      acc[14] = fmaf(mv, x3.z, acc[14]); acc[15] = fmaf(mv, x3.w, acc[15]);
    }

    float lm = acc[0];
#pragma unroll
    for (int i = 1; i < 16; ++i) lm = fmaxf(lm, acc[i]);
#pragma unroll
    for (int d = 1; d < 64; d <<= 1) lm = fmaxf(lm, __shfl_xor(lm, d));
    if ((tid & 63) == 0) red[w] = lm;
    __syncthreads();
    float bm = fmaxf(fmaxf(red[0], red[1]), fmaxf(red[2], red[3]));
    float inv = 1.f / bm;
    lsc += __logf(bm);
#pragma unroll
    for (int i = 0; i < 16; ++i)
      Xnxt[j * 68 + (w << 4) + i] = acc[i] * inv;
    __syncthreads();
    float* t = Xcur; Xcur = Xnxt; Xnxt = t;
  }

  float* out = Gout + (size_t)g * 4096;
  for (int idx = tid; idx < 4096; idx += 256) {
    int i = idx >> 6, r = idx & 63;
    out[idx] = Xcur[r * 68 + i];
  }
  if (tid == 0) {
    float s = lsc;
#pragma unroll
    for (int m = 0; m < 8; ++m) s += lscale[8 * g + m];
    glsc[g] = s;
  }
}

// ---------------- level-2 combine: 16 sequential mat-vecs ----------------
__global__ __launch_bounds__(256) void final_combine(
    const float* __restrict__ Gout, const float* __restrict__ glsc,
    const float* __restrict__ pe, const float* __restrict__ ps,
    const float* __restrict__ pb, float* __restrict__ out) {
  const int tid = threadIdx.x;
  const int j = tid & 63, w = tid >> 6;
  __shared__ float vsh[64];
  __shared__ float part[4 * 64];
  if (tid < 64) vsh[tid] = ps[tid] * pe[tid];   // f0
  __syncthreads();
  double lsc = 0.0;
  for (int gph = 0; gph < 16; ++gph) {
    const float* Gc = Gout + (size_t)gph * 4096;
    const int k0 = w << 4;
    float a0 = 0.f, a1 = 0.f, a2 = 0.f, a3 = 0.f;
#pragma unroll
    for (int kk = 0; kk < 16; kk += 4) {
      a0 = fmaf(vsh[k0 + kk + 0], Gc[(k0 + kk + 0) * 64 + j], a0);
      a1 = fmaf(vsh[k0 + kk + 1], Gc[(k0 + kk + 1) * 64 + j], a1);
      a2 = fmaf(vsh[k0 + kk + 2], Gc[(k0 + kk + 2) * 64 + j], a2);
      a3 = fmaf(vsh[k0 + kk + 3], Gc[(k0 + kk + 3) * 64 + j], a3);
    }
    part[w * 64 + j] = (a0 + a1) + (a2 + a3);
    __syncthreads();
    if (w == 0) {
      float u = part[j] + part[64 + j] + part[128 + j] + part[192 + j];
      float mx = u;
#pragma unroll
      for (int d = 1; d < 64; d <<= 1) mx = fmaxf(mx, __shfl_xor(mx, d));
      vsh[j] = u / mx;
      lsc += (double)__logf(mx) + (double)glsc[gph];
    }
    __syncthreads();
  }
  if (w == 0) {
    float z = vsh[j] * pb[T_LEN * 64 + j];
#pragma unroll
    for (int d = 1; d < 64; d <<= 1) z += __shfl_xor(z, d);
    if (j == 0) out[0] = (float)(-((double)logf(z) + lsc));
  }
}

extern "C" void kernel_launch(void* const* d_in, const int* in_sizes, int n_in,
                              void* d_out, int out_size, void* d_ws, size_t ws_size,
                              hipStream_t stream) {
  const float* s_i      = (const float*)d_in[0];
  const float* W_action = (const float*)d_in[1];
  const float* W_stop   = (const float*)d_in[2];
  const float* W_start  = (const float*)d_in[3];
  const int*   actions  = (const int*)d_in[4];

  char* ws = (char*)d_ws;
  u16*   s_bf  = (u16*)(ws + WS_SBF);
  u16*   wa_t  = (u16*)(ws + WS_WAT);
  u16*   wsm_t = (u16*)(ws + WS_WSMT);
  float* pe    = (float*)(ws + WS_PE);
  float* ps    = (float*)(ws + WS_PS);
  float* pb    = (float*)(ws + WS_PB);
  float* pc    = (float*)(ws + WS_PC);
  float* Mout  = (float*)(ws + WS_MOUT);
  float* lsc   = (float*)(ws + WS_LSC);
  float* Gout  = (float*)(ws + WS_GOUT);
  float* glsc  = (float*)(ws + WS_GLSC);

  conv_s<<<8256, 256, 0, stream>>>(s_i, s_bf);
  conv_wa<<<4096, 256, 0, stream>>>(W_action, wa_t);
  conv_wsm<<<192, 256, 0, stream>>>(W_stop, W_start, wsm_t);
  small_gemm<<<129, 256, 0, stream>>>(s_bf, wsm_t, ps, pb, pc);
  act_gemm<<<dim3(32, 64), 512, 0, stream>>>(s_bf, wa_t, actions, pe);
  chunk_kernel<<<128, 256, 0, stream>>>(pe, ps, pb, pc, Mout, lsc);
  group_combine<<<16, 256, 0, stream>>>(Mout, lsc, Gout, glsc);
  final_combine<<<1, 256, 0, stream>>>(Gout, glsc, pe, ps, pb, (float*)d_out);
}

// Round 9
// 167.930 us; speedup vs baseline: 2.5423x; 1.1528x over previous
//
#include <hip/hip_runtime.h>
#include <stdint.h>

// HMM trajectory-net forward:  -logsumexp over an 8191-step 64-state HMM scan.
// Pipeline:
//   conv_*       : fp32 -> bf16 repacks
//   small_gemm   : start/stop logits via MFMA, fused softmax/sigmoid -> ps, pb, pc
//   act_gemm     : barrier-free MFMA GEMM (B-group in LDS, A direct L2->VGPR),
//                  fused no-max softmax + action-select -> peT[b][t]
//   chunk_kernel : 128 chunks x 64 steps; 4 waves/chunk, 64x64 transfer matrix in
//                  registers; scalars staged in LDS (2-pass for peT layout)
//   group_combine: 16 blocks, each folds 8 chunk matrices via fp32 matmul chain
//   final_combine: 16 sequential mat-vecs (4-wave split) + boundary terms -> scalar

typedef short bf16x8 __attribute__((ext_vector_type(8)));
typedef float f32x4  __attribute__((ext_vector_type(4)));
typedef unsigned short u16;

#define T_LEN 8192
#define SDIM  256

// ---- workspace layout (bytes) ----
#define WS_SBF    0              // 8256*256 bf16 (padded rows zeroed)
#define WS_WAT    4227072        // 4096*256 bf16  [b*64+n][s]
#define WS_WSMT   6324224        // 192*256 bf16   [col][s]
#define WS_PE     6422528        // peT: 64*8192 f32  [b][t]
#define WS_PS     8519680        // 8193*64 f32
#define WS_PB     10617088       // 8193*64 f32
#define WS_PC     12714496       // 8193*64 f32   (dead after chunk_kernel -> reused for Gout)
#define WS_MOUT   14811904       // 128*4096 f32  [chunk][k][j]
#define WS_LSC    16909056       // 128 f32
#define WS_GOUT   WS_PC                      // 16*4096 f32 (reuses pc region)
#define WS_GLSC   (WS_PC + 262144)           // 16 f32

__device__ inline u16 f2bf(float f) {
  union { float f; uint32_t u; } v; v.f = f;
  uint32_t u = v.u;
  return (u16)((u + 0x7fffu + ((u >> 16) & 1u)) >> 16);
}

// ---------------- converts ----------------
__global__ void conv_s(const float* __restrict__ s_i, u16* __restrict__ s_bf) {
  int idx = blockIdx.x * 256 + threadIdx.x;
  int t = idx >> 8;
  float v = (t < T_LEN + 1) ? s_i[idx] : 0.f;
  s_bf[idx] = f2bf(v);
}

__global__ void conv_wa(const float* __restrict__ Wa, u16* __restrict__ wa_t) {
  int idx = blockIdx.x * 256 + threadIdx.x;
  int s = idx >> 12, bn = idx & 4095;
  wa_t[bn * 256 + s] = f2bf(Wa[idx]);
}

__global__ void conv_wsm(const float* __restrict__ Wstop, const float* __restrict__ Wstart,
                         u16* __restrict__ wsm_t) {
  int idx = blockIdx.x * 256 + threadIdx.x;
  int col = idx >> 8, s = idx & 255;
  float v;
  if (col < 64)       v = Wstart[s * 64 + col];
  else if (col < 128) v = Wstop[s * 128 + (col - 64) * 2 + 0];
  else                v = Wstop[s * 128 + (col - 128) * 2 + 1];
  wsm_t[col * 256 + s] = f2bf(v);
}

// ---------------- action GEMM + fused emit ----------------
// Tile 128(t) x 64(n = one b-group), K=256.  4 waves, each 32 t-rows.
// B-group staged once to LDS (32 KB, XOR-swizzled); A fragments loaded directly
// global->VGPR in two pre-issued batches.  ONE barrier total, no mid-loop syncs.
// Epilogue: no-max softmax (logits ~N(0,0.32^2)), pe = exp(v_sel)/sum(exp).
// Output transposed: peT[b][t] -> coalesced writes (32 consecutive t per wave).
__global__ __launch_bounds__(256, 4) void act_gemm(
    const u16* __restrict__ s_bf, const u16* __restrict__ wa_t,
    const int* __restrict__ actions, float* __restrict__ peT) {
  __shared__ uint4 ldsB[64 * 32];
  const int tid = threadIdx.x;
  const int lane = tid & 63;
  const int wm = tid >> 6;
  const int g = lane >> 4, c = lane & 15;

  // XCD-bijective swizzle (4096 % 8 == 0): each XCD gets 8 contiguous t-tiles
  int bid = blockIdx.x;
  int swz = (bid & 7) * 512 + (bid >> 3);
  const int t0 = (swz >> 6) * 128;
  const int b0 = swz & 63;

  const int tbase = t0 + wm * 32;

  // preload actions (8/thread)
  int act[2][4];
#pragma unroll
  for (int mf = 0; mf < 2; ++mf)
#pragma unroll
    for (int q = 0; q < 4; ++q)
      act[mf][q] = actions[tbase + mf * 16 + g * 4 + q];

  const u16* aRow0 = s_bf + (size_t)(tbase + c) * 256;
  const u16* aRow1 = s_bf + (size_t)(tbase + 16 + c) * 256;

  // batch 1: A fragments for ks 0..3
  bf16x8 af0[2][4];
#pragma unroll
  for (int ks = 0; ks < 4; ++ks) {
    af0[0][ks] = *(const bf16x8*)(aRow0 + ks * 32 + g * 8);
    af0[1][ks] = *(const bf16x8*)(aRow1 + ks * 32 + g * 8);
  }

  // stage B-group (64 rows x 256 k) into LDS, swizzled
  {
    const u16* bsrc = wa_t + (size_t)b0 * 64 * 256;
#pragma unroll
    for (int it = 0; it < 8; ++it) {
      int i = tid + 256 * it;
      int r = i >> 5, s = i & 31;
      ldsB[r * 32 + (s ^ (r & 7))] = *(const uint4*)(bsrc + r * 256 + s * 8);
    }
  }
  __syncthreads();

  f32x4 acc[2][4];
#pragma unroll
  for (int mf = 0; mf < 2; ++mf)
#pragma unroll
    for (int nf = 0; nf < 4; ++nf) acc[mf][nf] = (f32x4){0.f, 0.f, 0.f, 0.f};

  // batch 2: A fragments for ks 4..7 (latency hides under first compute half)
  bf16x8 af1[2][4];
#pragma unroll
  for (int ks = 0; ks < 4; ++ks) {
    af1[0][ks] = *(const bf16x8*)(aRow0 + 128 + ks * 32 + g * 8);
    af1[1][ks] = *(const bf16x8*)(aRow1 + 128 + ks * 32 + g * 8);
  }

  // compute: ks 0..3
#pragma unroll
  for (int ks = 0; ks < 4; ++ks) {
#pragma unroll
    for (int nf = 0; nf < 4; ++nf) {
      int rr = nf * 16 + c;
      bf16x8 bfv = *(const bf16x8*)&ldsB[rr * 32 + ((ks * 4 + g) ^ (rr & 7))];
      acc[0][nf] = __builtin_amdgcn_mfma_f32_16x16x32_bf16(af0[0][ks], bfv, acc[0][nf], 0, 0, 0);
      acc[1][nf] = __builtin_amdgcn_mfma_f32_16x16x32_bf16(af0[1][ks], bfv, acc[1][nf], 0, 0, 0);
    }
  }
  // compute: ks 4..7
#pragma unroll
  for (int ks = 0; ks < 4; ++ks) {
#pragma unroll
    for (int nf = 0; nf < 4; ++nf) {
      int rr = nf * 16 + c;
      bf16x8 bfv = *(const bf16x8*)&ldsB[rr * 32 + (((ks + 4) * 4 + g) ^ (rr & 7))];
      acc[0][nf] = __builtin_amdgcn_mfma_f32_16x16x32_bf16(af1[0][ks], bfv, acc[0][nf], 0, 0, 0);
      acc[1][nf] = __builtin_amdgcn_mfma_f32_16x16x32_bf16(af1[1][ks], bfv, acc[1][nf], 0, 0, 0);
    }
  }

  // epilogue: row r = g*4+q lives in 16 lanes (fixed g) x 4 nf regs.
  // no-max softmax: s = sum exp(v);  pe = exp(v_sel)/s.
  const size_t pebase = (size_t)b0 * 8192;
#pragma unroll
  for (int mf = 0; mf < 2; ++mf) {
#pragma unroll
    for (int q = 0; q < 4; ++q) {
      float e0 = __expf(acc[mf][0][q]);
      float e1 = __expf(acc[mf][1][q]);
      float e2 = __expf(acc[mf][2][q]);
      float e3 = __expf(acc[mf][3][q]);
      float s = (e0 + e1) + (e2 + e3);
#pragma unroll
      for (int d = 1; d < 16; d <<= 1) s += __shfl_xor(s, d);
      int a = act[mf][q];
      int acf = a >> 4;
      float esel = (acf == 0) ? e0 : (acf == 1) ? e1 : (acf == 2) ? e2 : e3;
      if (c == (a & 15))
        peT[pebase + tbase + mf * 16 + g * 4 + q] = esel / s;
    }
  }
}

// ---------------- start/stop GEMM + fused softmax/sigmoid ----------------
__global__ __launch_bounds__(256) void small_gemm(
    const u16* __restrict__ s_bf, const u16* __restrict__ wsm_t,
    float* __restrict__ ps, float* __restrict__ pb, float* __restrict__ pc) {
  __shared__ uint4 ldsA[64 * 16];
  __shared__ uint4 ldsB[192 * 16];
  const int t0 = blockIdx.x * 64;
  const int tid = threadIdx.x;
  const int lane = tid & 63, w = tid >> 6;
  const int g = lane >> 4, c = lane & 15;

  f32x4 acc[12];
#pragma unroll
  for (int i = 0; i < 12; ++i) acc[i] = (f32x4){0.f, 0.f, 0.f, 0.f};

  for (int kh = 0; kh < 2; ++kh) {
    if (kh) __syncthreads();
    for (int i = tid; i < 64 * 16; i += 256) {
      int row = i >> 4, u = i & 15;
      ldsA[(row * 16 + u) ^ (row & 7)] =
          *(const uint4*)(s_bf + (size_t)(t0 + row) * 256 + kh * 128 + u * 8);
    }
    for (int i = tid; i < 192 * 16; i += 256) {
      int row = i >> 4, u = i & 15;
      ldsB[(row * 16 + u) ^ (row & 7)] =
          *(const uint4*)(wsm_t + (size_t)row * 256 + kh * 128 + u * 8);
    }
    __syncthreads();
#pragma unroll
    for (int kk = 0; kk < 4; ++kk) {
      int u = kk * 4 + g;
      int arow = w * 16 + c;
      bf16x8 af = *(const bf16x8*)&ldsA[(arow * 16 + u) ^ (arow & 7)];
#pragma unroll
      for (int cf = 0; cf < 12; ++cf) {
        int brow = cf * 16 + c;
        bf16x8 bfr = *(const bf16x8*)&ldsB[(brow * 16 + u) ^ (brow & 7)];
        acc[cf] = __builtin_amdgcn_mfma_f32_16x16x32_bf16(af, bfr, acc[cf], 0, 0, 0);
      }
    }
  }

#pragma unroll
  for (int q = 0; q < 4; ++q) {
    int t = t0 + w * 16 + g * 4 + q;
    float v0 = acc[0][q], v1 = acc[1][q], v2 = acc[2][q], v3 = acc[3][q];
    float m = fmaxf(fmaxf(v0, v1), fmaxf(v2, v3));
#pragma unroll
    for (int d = 1; d < 16; d <<= 1) m = fmaxf(m, __shfl_xor(m, d));
    float s = __expf(v0 - m) + __expf(v1 - m) + __expf(v2 - m) + __expf(v3 - m);
#pragma unroll
    for (int d = 1; d < 16; d <<= 1) s += __shfl_xor(s, d);
    float lse = m + __logf(s);
    if (t <= T_LEN) {
      ps[t * 64 + 0 * 16 + c] = __expf(v0 - lse);
      ps[t * 64 + 1 * 16 + c] = __expf(v1 - lse);
      ps[t * 64 + 2 * 16 + c] = __expf(v2 - lse);
      ps[t * 64 + 3 * 16 + c] = __expf(v3 - lse);
#pragma unroll
      for (int bf = 0; bf < 4; ++bf) {
        float l0 = acc[4 + bf][q], l1 = acc[8 + bf][q];
        float d01 = l0 - l1;
        pb[t * 64 + bf * 16 + c] = 1.f / (1.f + __expf(-d01));
        pc[t * 64 + bf * 16 + c] = 1.f / (1.f + __expf(d01));
      }
    }
  }
}

// ---------------- chunked scan: 4 waves per chunk ----------------
// scal stride 196 (not 192): keeps float4 alignment, breaks bank aliasing of the
// pass-2 strided RMW.  Pass 1 stages b,c,s from [t][64] arrays (coalesced);
// pass 2 folds e from peT[b][t] (coalesced on that layout).
__global__ __launch_bounds__(256) void chunk_kernel(
    const float* __restrict__ peT, const float* __restrict__ ps,
    const float* __restrict__ pb, const float* __restrict__ pc,
    float* __restrict__ Mout, float* __restrict__ lscale) {
  __shared__ float scal[64 * 196];   // per step: [b(64) | ec(64) | es(64) | pad]
  __shared__ float part[2][256];
  __shared__ float mxs[4];
  const int ck = blockIdx.x;
  const int tid = threadIdx.x;
  const int lane = tid & 63;
  const int w = tid >> 6;
  const int tlo = ck * 64 + 1;

#pragma unroll
  for (int it = 0; it < 16; ++it) {
    int i = tid + 256 * it;
    int st = i >> 6, j = i & 63;
    int t = tlo + st;
    if (t <= T_LEN - 1) {
      int base = t * 64 + j;
      scal[st * 196 + j]       = pb[base];
      scal[st * 196 + 64 + j]  = pc[base];
      scal[st * 196 + 128 + j] = ps[base];
    } else {
      scal[st * 196 + j]       = 0.f;
      scal[st * 196 + 64 + j]  = 1.f;
      scal[st * 196 + 128 + j] = 0.f;
    }
  }
  __syncthreads();
#pragma unroll
  for (int it = 0; it < 16; ++it) {
    int i = tid + 256 * it;
    int j = i >> 6, st = i & 63;
    int t = tlo + st;
    if (t <= T_LEN - 1) {
      float e = peT[(size_t)j * 8192 + t];
      scal[st * 196 + 64 + j]  *= e;
      scal[st * 196 + 128 + j] *= e;
    }
  }
  __syncthreads();

  float M[16];
#pragma unroll
  for (int jj = 0; jj < 16; ++jj) M[jj] = ((w * 16 + jj) == lane) ? 1.f : 0.f;
  float lsc = 0.f;
  int pbuf = 0;

  for (int st = 0; st < 64; ++st) {
    const float* sb = &scal[st * 196];
    float p0 = 0.f, p1 = 0.f, p2 = 0.f, p3 = 0.f;
#pragma unroll
    for (int q = 0; q < 4; ++q) {
      float4 bq = *(const float4*)(sb + w * 16 + q * 4);
      p0 = fmaf(bq.x, M[q * 4 + 0], p0);
      p1 = fmaf(bq.y, M[q * 4 + 1], p1);
      p2 = fmaf(bq.z, M[q * 4 + 2], p2);
      p3 = fmaf(bq.w, M[q * 4 + 3], p3);
    }
    part[pbuf][w * 64 + lane] = (p0 + p1) + (p2 + p3);
    __syncthreads();
    float wv = part[pbuf][lane] + part[pbuf][64 + lane] +
               part[pbuf][128 + lane] + part[pbuf][192 + lane];
    pbuf ^= 1;
#pragma unroll
    for (int q = 0; q < 4; ++q) {
      float4 ecq = *(const float4*)(sb + 64 + w * 16 + q * 4);
      float4 esq = *(const float4*)(sb + 128 + w * 16 + q * 4);
      M[q * 4 + 0] = fmaf(ecq.x, M[q * 4 + 0], esq.x * wv);
      M[q * 4 + 1] = fmaf(ecq.y, M[q * 4 + 1], esq.y * wv);
      M[q * 4 + 2] = fmaf(ecq.z, M[q * 4 + 2], esq.z * wv);
      M[q * 4 + 3] = fmaf(ecq.w, M[q * 4 + 3], esq.w * wv);
    }
    if ((st & 7) == 7) {
      float mx = M[0];
#pragma unroll
      for (int jj = 1; jj < 16; ++jj) mx = fmaxf(mx, M[jj]);
#pragma unroll
      for (int d = 1; d < 64; d <<= 1) mx = fmaxf(mx, __shfl_xor(mx, d));
      if (lane == 0) mxs[w] = mx;
      __syncthreads();
      float bm = fmaxf(fmaxf(mxs[0], mxs[1]), fmaxf(mxs[2], mxs[3]));
      float inv = 1.f / bm;
#pragma unroll
      for (int jj = 0; jj < 16; ++jj) M[jj] *= inv;
      lsc += __logf(bm);
    }
  }

  float* out = Mout + (size_t)ck * 4096;
#pragma unroll
  for (int q = 0; q < 4; ++q) {
    float4 v = make_float4(M[q * 4 + 0], M[q * 4 + 1], M[q * 4 + 2], M[q * 4 + 3]);
    *(float4*)(out + lane * 64 + w * 16 + q * 4) = v;
  }
  if (tid == 0) lscale[ck] = lsc;
}

// ---------------- level-1 combine: 16 groups x 8 chunk matrices ----------------
__global__ __launch_bounds__(256) void group_combine(
    const float* __restrict__ Mout, const float* __restrict__ lscale,
    float* __restrict__ Gout, float* __restrict__ glsc) {
  const int g = blockIdx.x;
  const int tid = threadIdx.x;
  const int j = tid & 63;
  const int w = tid >> 6;
  __shared__ float Xa[64 * 68];
  __shared__ float Xb[64 * 68];
  __shared__ float red[4];

  const float* M0 = Mout + (size_t)(8 * g) * 4096;
  for (int idx = tid; idx < 4096; idx += 256) {
    int i = idx >> 6, r = idx & 63;
    Xa[r * 68 + i] = M0[idx];
  }
  __syncthreads();

  float lsc = 0.f;
  float* Xcur = Xa;
  float* Xnxt = Xb;

  for (int m = 1; m < 8; ++m) {
    const float* Mc = Mout + (size_t)(8 * g + m) * 4096;
    float acc[16];
#pragma unroll
    for (int i = 0; i < 16; ++i) acc[i] = 0.f;

    for (int k = 0; k < 64; ++k) {
      float mv = Mc[k * 64 + j];
      const float* xr = Xcur + k * 68 + (w << 4);
      float4 x0 = *(const float4*)(xr + 0);
      float4 x1 = *(const float4*)(xr + 4);
      float4 x2 = *(const float4*)(xr + 8);
      float4 x3 = *(const float4*)(xr + 12);
      acc[0]  = fmaf(mv, x0.x, acc[0]);  acc[1]  = fmaf(mv, x0.y, acc[1]);
      acc[2]  = fmaf(mv, x0.z, acc[2]);  acc[3]  = fmaf(mv, x0.w, acc[3]);
      acc[4]  = fmaf(mv, x1.x, acc[4]);  acc[5]  = fmaf(mv, x1.y, acc[5]);
      acc[6]  = fmaf(mv, x1.z, acc[6]);  acc[7]  = fmaf(mv, x1.w, acc[7]);
      acc[8]  = fmaf(mv, x2.x, acc[8]);  acc[9]  = fmaf(mv, x2.y, acc[9]);
      acc[10] = fmaf(mv, x2.z, acc[10]); acc[11] = fmaf(mv, x2.w, acc[11]);
      acc[12] = fmaf(mv, x3.x, acc[12]); acc[13] = fmaf(mv, x3.y, acc[13]);
      acc[14] = fmaf(mv, x3.z, acc[14]); acc[15] = fmaf(mv, x3.w, acc[15]);
    }

    float lm = acc[0];
#pragma unroll
    for (int i = 1; i < 16; ++i) lm = fmaxf(lm, acc[i]);
#pragma unroll
    for (int d = 1; d < 64; d <<= 1) lm = fmaxf(lm, __shfl_xor(lm, d));
    if ((tid & 63) == 0) red[w] = lm;
    __syncthreads();
    float bm = fmaxf(fmaxf(red[0], red[1]), fmaxf(red[2], red[3]));
    float inv = 1.f / bm;
    lsc += __logf(bm);
#pragma unroll
    for (int i = 0; i < 16; ++i)
      Xnxt[j * 68 + (w << 4) + i] = acc[i] * inv;
    __syncthreads();
    float* t = Xcur; Xcur = Xnxt; Xnxt = t;
  }

  float* out = Gout + (size_t)g * 4096;
  for (int idx = tid; idx < 4096; idx += 256) {
    int i = idx >> 6, r = idx & 63;
    out[idx] = Xcur[r * 68 + i];
  }
  if (tid == 0) {
    float s = lsc;
#pragma unroll
    for (int m = 0; m < 8; ++m) s += lscale[8 * g + m];
    glsc[g] = s;
  }
}

// ---------------- level-2 combine: 16 sequential mat-vecs ----------------
__global__ __launch_bounds__(256) void final_combine(
    const float* __restrict__ Gout, const float* __restrict__ glsc,
    const float* __restrict__ peT, const float* __restrict__ ps,
    const float* __restrict__ pb, float* __restrict__ out) {
  const int tid = threadIdx.x;
  const int j = tid & 63, w = tid >> 6;
  __shared__ float vsh[64];
  __shared__ float part[4 * 64];
  if (tid < 64) vsh[tid] = ps[tid] * peT[(size_t)tid * 8192];   // f0
  __syncthreads();
  double lsc = 0.0;
  for (int gph = 0; gph < 16; ++gph) {
    const float* Gc = Gout + (size_t)gph * 4096;
    const int k0 = w << 4;
    float a0 = 0.f, a1 = 0.f, a2 = 0.f, a3 = 0.f;
#pragma unroll
    for (int kk = 0; kk < 16; kk += 4) {
      a0 = fmaf(vsh[k0 + kk + 0], Gc[(k0 + kk + 0) * 64 + j], a0);
      a1 = fmaf(vsh[k0 + kk + 1], Gc[(k0 + kk + 1) * 64 + j], a1);
      a2 = fmaf(vsh[k0 + kk + 2], Gc[(k0 + kk + 2) * 64 + j], a2);
      a3 = fmaf(vsh[k0 + kk + 3], Gc[(k0 + kk + 3) * 64 + j], a3);
    }
    part[w * 64 + j] = (a0 + a1) + (a2 + a3);
    __syncthreads();
    if (w == 0) {
      float u = part[j] + part[64 + j] + part[128 + j] + part[192 + j];
      float mx = u;
#pragma unroll
      for (int d = 1; d < 64; d <<= 1) mx = fmaxf(mx, __shfl_xor(mx, d));
      vsh[j] = u / mx;
      lsc += (double)__logf(mx) + (double)glsc[gph];
    }
    __syncthreads();
  }
  if (w == 0) {
    float z = vsh[j] * pb[T_LEN * 64 + j];
#pragma unroll
    for (int d = 1; d < 64; d <<= 1) z += __shfl_xor(z, d);
    if (j == 0) out[0] = (float)(-((double)logf(z) + lsc));
  }
}

extern "C" void kernel_launch(void* const* d_in, const int* in_sizes, int n_in,
                              void* d_out, int out_size, void* d_ws, size_t ws_size,
                              hipStream_t stream) {
  const float* s_i      = (const float*)d_in[0];
  const float* W_action = (const float*)d_in[1];
  const float* W_stop   = (const float*)d_in[2];
  const float* W_start  = (const float*)d_in[3];
  const int*   actions  = (const int*)d_in[4];

  char* ws = (char*)d_ws;
  u16*   s_bf  = (u16*)(ws + WS_SBF);
  u16*   wa_t  = (u16*)(ws + WS_WAT);
  u16*   wsm_t = (u16*)(ws + WS_WSMT);
  float* peT   = (float*)(ws + WS_PE);
  float* ps    = (float*)(ws + WS_PS);
  float* pb    = (float*)(ws + WS_PB);
  float* pc    = (float*)(ws + WS_PC);
  float* Mout  = (float*)(ws + WS_MOUT);
  float* lsc   = (float*)(ws + WS_LSC);
  float* Gout  = (float*)(ws + WS_GOUT);
  float* glsc  = (float*)(ws + WS_GLSC);

  conv_s<<<8256, 256, 0, stream>>>(s_i, s_bf);
  conv_wa<<<4096, 256, 0, stream>>>(W_action, wa_t);
  conv_wsm<<<192, 256, 0, stream>>>(W_stop, W_start, wsm_t);
  small_gemm<<<129, 256, 0, stream>>>(s_bf, wsm_t, ps, pb, pc);
  act_gemm<<<4096, 256, 0, stream>>>(s_bf, wa_t, actions, peT);
  chunk_kernel<<<128, 256, 0, stream>>>(peT, ps, pb, pc, Mout, lsc);
  group_combine<<<16, 256, 0, stream>>>(Mout, lsc, Gout, glsc);
  final_combine<<<1, 256, 0, stream>>>(Gout, glsc, peT, ps, pb, (float*)d_out);
}

// Round 10
// 152.870 us; speedup vs baseline: 2.7927x; 1.0985x over previous
//
#include <hip/hip_runtime.h>
#include <stdint.h>

// HMM trajectory-net forward:  -logsumexp over an 8191-step 64-state HMM scan.
// Pipeline:
//   conv_*       : fp32 -> bf16 repacks
//   small_gemm   : start/stop logits via MFMA, fused softmax/sigmoid -> ps, pb, pc
//   act_gemm     : barrier-free MFMA GEMM (B-group in LDS, A direct L2->VGPR),
//                  fused no-max softmax + action-select -> peT[b][t]
//   chunk_kernel : 128 chunks x 64 steps; 4 waves/chunk, 64x64 transfer matrix in
//                  registers; scalars staged in LDS (2-pass for peT layout)
//   group_combine: 16 blocks x 7 matmuls, LDS-resident operands, double-buffered
//                  global->LDS prefetch of the next matrix (latency hidden)
//   final_combine: 16 sequential mat-vecs (4-wave split) + boundary terms -> scalar

typedef short bf16x8 __attribute__((ext_vector_type(8)));
typedef float f32x4  __attribute__((ext_vector_type(4)));
typedef unsigned short u16;

#define T_LEN 8192
#define SDIM  256

// ---- workspace layout (bytes) ----
#define WS_SBF    0              // 8256*256 bf16 (padded rows zeroed)
#define WS_WAT    4227072        // 4096*256 bf16  [b*64+n][s]
#define WS_WSMT   6324224        // 192*256 bf16   [col][s]
#define WS_PE     6422528        // peT: 64*8192 f32  [b][t]
#define WS_PS     8519680        // 8193*64 f32
#define WS_PB     10617088       // 8193*64 f32
#define WS_PC     12714496       // 8193*64 f32   (dead after chunk_kernel -> reused for Gout)
#define WS_MOUT   14811904       // 128*4096 f32  [chunk][k][j]
#define WS_LSC    16909056       // 128 f32
#define WS_GOUT   WS_PC                      // 16*4096 f32 (reuses pc region)
#define WS_GLSC   (WS_PC + 262144)           // 16 f32

__device__ inline u16 f2bf(float f) {
  union { float f; uint32_t u; } v; v.f = f;
  uint32_t u = v.u;
  return (u16)((u + 0x7fffu + ((u >> 16) & 1u)) >> 16);
}

// ---------------- converts ----------------
__global__ void conv_s(const float* __restrict__ s_i, u16* __restrict__ s_bf) {
  int idx = blockIdx.x * 256 + threadIdx.x;
  int t = idx >> 8;
  float v = (t < T_LEN + 1) ? s_i[idx] : 0.f;
  s_bf[idx] = f2bf(v);
}

__global__ void conv_wa(const float* __restrict__ Wa, u16* __restrict__ wa_t) {
  int idx = blockIdx.x * 256 + threadIdx.x;
  int s = idx >> 12, bn = idx & 4095;
  wa_t[bn * 256 + s] = f2bf(Wa[idx]);
}

__global__ void conv_wsm(const float* __restrict__ Wstop, const float* __restrict__ Wstart,
                         u16* __restrict__ wsm_t) {
  int idx = blockIdx.x * 256 + threadIdx.x;
  int col = idx >> 8, s = idx & 255;
  float v;
  if (col < 64)       v = Wstart[s * 64 + col];
  else if (col < 128) v = Wstop[s * 128 + (col - 64) * 2 + 0];
  else                v = Wstop[s * 128 + (col - 128) * 2 + 1];
  wsm_t[col * 256 + s] = f2bf(v);
}

// ---------------- action GEMM + fused emit ----------------
// Tile 128(t) x 64(n = one b-group), K=256.  4 waves, each 32 t-rows.
// B-group staged once to LDS (32 KB, XOR-swizzled); A fragments loaded directly
// global->VGPR in two pre-issued batches.  ONE barrier total, no mid-loop syncs.
// Epilogue: no-max softmax (logits ~N(0,0.32^2)), pe = exp(v_sel)/sum(exp).
// Output transposed: peT[b][t] -> coalesced writes (32 consecutive t per wave).
__global__ __launch_bounds__(256, 4) void act_gemm(
    const u16* __restrict__ s_bf, const u16* __restrict__ wa_t,
    const int* __restrict__ actions, float* __restrict__ peT) {
  __shared__ uint4 ldsB[64 * 32];
  const int tid = threadIdx.x;
  const int lane = tid & 63;
  const int wm = tid >> 6;
  const int g = lane >> 4, c = lane & 15;

  // XCD-bijective swizzle (4096 % 8 == 0): each XCD gets 8 contiguous t-tiles
  int bid = blockIdx.x;
  int swz = (bid & 7) * 512 + (bid >> 3);
  const int t0 = (swz >> 6) * 128;
  const int b0 = swz & 63;

  const int tbase = t0 + wm * 32;

  // preload actions (8/thread)
  int act[2][4];
#pragma unroll
  for (int mf = 0; mf < 2; ++mf)
#pragma unroll
    for (int q = 0; q < 4; ++q)
      act[mf][q] = actions[tbase + mf * 16 + g * 4 + q];

  const u16* aRow0 = s_bf + (size_t)(tbase + c) * 256;
  const u16* aRow1 = s_bf + (size_t)(tbase + 16 + c) * 256;

  // batch 1: A fragments for ks 0..3
  bf16x8 af0[2][4];
#pragma unroll
  for (int ks = 0; ks < 4; ++ks) {
    af0[0][ks] = *(const bf16x8*)(aRow0 + ks * 32 + g * 8);
    af0[1][ks] = *(const bf16x8*)(aRow1 + ks * 32 + g * 8);
  }

  // stage B-group (64 rows x 256 k) into LDS, swizzled
  {
    const u16* bsrc = wa_t + (size_t)b0 * 64 * 256;
#pragma unroll
    for (int it = 0; it < 8; ++it) {
      int i = tid + 256 * it;
      int r = i >> 5, s = i & 31;
      ldsB[r * 32 + (s ^ (r & 7))] = *(const uint4*)(bsrc + r * 256 + s * 8);
    }
  }
  __syncthreads();

  f32x4 acc[2][4];
#pragma unroll
  for (int mf = 0; mf < 2; ++mf)
#pragma unroll
    for (int nf = 0; nf < 4; ++nf) acc[mf][nf] = (f32x4){0.f, 0.f, 0.f, 0.f};

  // batch 2: A fragments for ks 4..7 (latency hides under first compute half)
  bf16x8 af1[2][4];
#pragma unroll
  for (int ks = 0; ks < 4; ++ks) {
    af1[0][ks] = *(const bf16x8*)(aRow0 + 128 + ks * 32 + g * 8);
    af1[1][ks] = *(const bf16x8*)(aRow1 + 128 + ks * 32 + g * 8);
  }

  // compute: ks 0..3
#pragma unroll
  for (int ks = 0; ks < 4; ++ks) {
#pragma unroll
    for (int nf = 0; nf < 4; ++nf) {
      int rr = nf * 16 + c;
      bf16x8 bfv = *(const bf16x8*)&ldsB[rr * 32 + ((ks * 4 + g) ^ (rr & 7))];
      acc[0][nf] = __builtin_amdgcn_mfma_f32_16x16x32_bf16(af0[0][ks], bfv, acc[0][nf], 0, 0, 0);
      acc[1][nf] = __builtin_amdgcn_mfma_f32_16x16x32_bf16(af0[1][ks], bfv, acc[1][nf], 0, 0, 0);
    }
  }
  // compute: ks 4..7
#pragma unroll
  for (int ks = 0; ks < 4; ++ks) {
#pragma unroll
    for (int nf = 0; nf < 4; ++nf) {
      int rr = nf * 16 + c;
      bf16x8 bfv = *(const bf16x8*)&ldsB[rr * 32 + (((ks + 4) * 4 + g) ^ (rr & 7))];
      acc[0][nf] = __builtin_amdgcn_mfma_f32_16x16x32_bf16(af1[0][ks], bfv, acc[0][nf], 0, 0, 0);
      acc[1][nf] = __builtin_amdgcn_mfma_f32_16x16x32_bf16(af1[1][ks], bfv, acc[1][nf], 0, 0, 0);
    }
  }

  // epilogue: no-max softmax;  pe = exp(v_sel)/s; transposed coalesced writes
  const size_t pebase = (size_t)b0 * 8192;
#pragma unroll
  for (int mf = 0; mf < 2; ++mf) {
#pragma unroll
    for (int q = 0; q < 4; ++q) {
      float e0 = __expf(acc[mf][0][q]);
      float e1 = __expf(acc[mf][1][q]);
      float e2 = __expf(acc[mf][2][q]);
      float e3 = __expf(acc[mf][3][q]);
      float s = (e0 + e1) + (e2 + e3);
#pragma unroll
      for (int d = 1; d < 16; d <<= 1) s += __shfl_xor(s, d);
      int a = act[mf][q];
      int acf = a >> 4;
      float esel = (acf == 0) ? e0 : (acf == 1) ? e1 : (acf == 2) ? e2 : e3;
      if (c == (a & 15))
        peT[pebase + tbase + mf * 16 + g * 4 + q] = esel / s;
    }
  }
}

// ---------------- start/stop GEMM + fused softmax/sigmoid ----------------
__global__ __launch_bounds__(256) void small_gemm(
    const u16* __restrict__ s_bf, const u16* __restrict__ wsm_t,
    float* __restrict__ ps, float* __restrict__ pb, float* __restrict__ pc) {
  __shared__ uint4 ldsA[64 * 16];
  __shared__ uint4 ldsB[192 * 16];
  const int t0 = blockIdx.x * 64;
  const int tid = threadIdx.x;
  const int lane = tid & 63, w = tid >> 6;
  const int g = lane >> 4, c = lane & 15;

  f32x4 acc[12];
#pragma unroll
  for (int i = 0; i < 12; ++i) acc[i] = (f32x4){0.f, 0.f, 0.f, 0.f};

  for (int kh = 0; kh < 2; ++kh) {
    if (kh) __syncthreads();
    for (int i = tid; i < 64 * 16; i += 256) {
      int row = i >> 4, u = i & 15;
      ldsA[(row * 16 + u) ^ (row & 7)] =
          *(const uint4*)(s_bf + (size_t)(t0 + row) * 256 + kh * 128 + u * 8);
    }
    for (int i = tid; i < 192 * 16; i += 256) {
      int row = i >> 4, u = i & 15;
      ldsB[(row * 16 + u) ^ (row & 7)] =
          *(const uint4*)(wsm_t + (size_t)row * 256 + kh * 128 + u * 8);
    }
    __syncthreads();
#pragma unroll
    for (int kk = 0; kk < 4; ++kk) {
      int u = kk * 4 + g;
      int arow = w * 16 + c;
      bf16x8 af = *(const bf16x8*)&ldsA[(arow * 16 + u) ^ (arow & 7)];
#pragma unroll
      for (int cf = 0; cf < 12; ++cf) {
        int brow = cf * 16 + c;
        bf16x8 bfr = *(const bf16x8*)&ldsB[(brow * 16 + u) ^ (brow & 7)];
        acc[cf] = __builtin_amdgcn_mfma_f32_16x16x32_bf16(af, bfr, acc[cf], 0, 0, 0);
      }
    }
  }

#pragma unroll
  for (int q = 0; q < 4; ++q) {
    int t = t0 + w * 16 + g * 4 + q;
    float v0 = acc[0][q], v1 = acc[1][q], v2 = acc[2][q], v3 = acc[3][q];
    float m = fmaxf(fmaxf(v0, v1), fmaxf(v2, v3));
#pragma unroll
    for (int d = 1; d < 16; d <<= 1) m = fmaxf(m, __shfl_xor(m, d));
    float s = __expf(v0 - m) + __expf(v1 - m) + __expf(v2 - m) + __expf(v3 - m);
#pragma unroll
    for (int d = 1; d < 16; d <<= 1) s += __shfl_xor(s, d);
    float lse = m + __logf(s);
    if (t <= T_LEN) {
      ps[t * 64 + 0 * 16 + c] = __expf(v0 - lse);
      ps[t * 64 + 1 * 16 + c] = __expf(v1 - lse);
      ps[t * 64 + 2 * 16 + c] = __expf(v2 - lse);
      ps[t * 64 + 3 * 16 + c] = __expf(v3 - lse);
#pragma unroll
      for (int bf = 0; bf < 4; ++bf) {
        float l0 = acc[4 + bf][q], l1 = acc[8 + bf][q];
        float d01 = l0 - l1;
        pb[t * 64 + bf * 16 + c] = 1.f / (1.f + __expf(-d01));
        pc[t * 64 + bf * 16 + c] = 1.f / (1.f + __expf(d01));
      }
    }
  }
}

// ---------------- chunked scan: 4 waves per chunk ----------------
__global__ __launch_bounds__(256) void chunk_kernel(
    const float* __restrict__ peT, const float* __restrict__ ps,
    const float* __restrict__ pb, const float* __restrict__ pc,
    float* __restrict__ Mout, float* __restrict__ lscale) {
  __shared__ float scal[64 * 196];   // per step: [b(64) | ec(64) | es(64) | pad]
  __shared__ float part[2][256];
  __shared__ float mxs[4];
  const int ck = blockIdx.x;
  const int tid = threadIdx.x;
  const int lane = tid & 63;
  const int w = tid >> 6;
  const int tlo = ck * 64 + 1;

#pragma unroll
  for (int it = 0; it < 16; ++it) {
    int i = tid + 256 * it;
    int st = i >> 6, j = i & 63;
    int t = tlo + st;
    if (t <= T_LEN - 1) {
      int base = t * 64 + j;
      scal[st * 196 + j]       = pb[base];
      scal[st * 196 + 64 + j]  = pc[base];
      scal[st * 196 + 128 + j] = ps[base];
    } else {
      scal[st * 196 + j]       = 0.f;
      scal[st * 196 + 64 + j]  = 1.f;
      scal[st * 196 + 128 + j] = 0.f;
    }
  }
  __syncthreads();
#pragma unroll
  for (int it = 0; it < 16; ++it) {
    int i = tid + 256 * it;
    int j = i >> 6, st = i & 63;
    int t = tlo + st;
    if (t <= T_LEN - 1) {
      float e = peT[(size_t)j * 8192 + t];
      scal[st * 196 + 64 + j]  *= e;
      scal[st * 196 + 128 + j] *= e;
    }
  }
  __syncthreads();

  float M[16];
#pragma unroll
  for (int jj = 0; jj < 16; ++jj) M[jj] = ((w * 16 + jj) == lane) ? 1.f : 0.f;
  float lsc = 0.f;
  int pbuf = 0;

  for (int st = 0; st < 64; ++st) {
    const float* sb = &scal[st * 196];
    float p0 = 0.f, p1 = 0.f, p2 = 0.f, p3 = 0.f;
#pragma unroll
    for (int q = 0; q < 4; ++q) {
      float4 bq = *(const float4*)(sb + w * 16 + q * 4);
      p0 = fmaf(bq.x, M[q * 4 + 0], p0);
      p1 = fmaf(bq.y, M[q * 4 + 1], p1);
      p2 = fmaf(bq.z, M[q * 4 + 2], p2);
      p3 = fmaf(bq.w, M[q * 4 + 3], p3);
    }
    part[pbuf][w * 64 + lane] = (p0 + p1) + (p2 + p3);
    __syncthreads();
    float wv = part[pbuf][lane] + part[pbuf][64 + lane] +
               part[pbuf][128 + lane] + part[pbuf][192 + lane];
    pbuf ^= 1;
#pragma unroll
    for (int q = 0; q < 4; ++q) {
      float4 ecq = *(const float4*)(sb + 64 + w * 16 + q * 4);
      float4 esq = *(const float4*)(sb + 128 + w * 16 + q * 4);
      M[q * 4 + 0] = fmaf(ecq.x, M[q * 4 + 0], esq.x * wv);
      M[q * 4 + 1] = fmaf(ecq.y, M[q * 4 + 1], esq.y * wv);
      M[q * 4 + 2] = fmaf(ecq.z, M[q * 4 + 2], esq.z * wv);
      M[q * 4 + 3] = fmaf(ecq.w, M[q * 4 + 3], esq.w * wv);
    }
    if ((st & 7) == 7) {
      float mx = M[0];
#pragma unroll
      for (int jj = 1; jj < 16; ++jj) mx = fmaxf(mx, M[jj]);
#pragma unroll
      for (int d = 1; d < 64; d <<= 1) mx = fmaxf(mx, __shfl_xor(mx, d));
      if (lane == 0) mxs[w] = mx;
      __syncthreads();
      float bm = fmaxf(fmaxf(mxs[0], mxs[1]), fmaxf(mxs[2], mxs[3]));
      float inv = 1.f / bm;
#pragma unroll
      for (int jj = 0; jj < 16; ++jj) M[jj] *= inv;
      lsc += __logf(bm);
    }
  }

  float* out = Mout + (size_t)ck * 4096;
#pragma unroll
  for (int q = 0; q < 4; ++q) {
    float4 v = make_float4(M[q * 4 + 0], M[q * 4 + 1], M[q * 4 + 2], M[q * 4 + 3]);
    *(float4*)(out + lane * 64 + w * 16 + q * 4) = v;
  }
  if (tid == 0) lscale[ck] = lsc;
}

// ---------------- level-1 combine: 16 groups x 8 chunk matrices ----------------
// LDS-resident operands + double-buffered prefetch of the next matrix.
// Mout[ck][i][j] = M_ck[j][i].  X layout: X[r][c] at Xa[r*68+c].
// Mcur layout: Mcur[k*68 + j] = M_m[j][k]  (linear copy of Mout[ck]).
__global__ __launch_bounds__(256) void group_combine(
    const float* __restrict__ Mout, const float* __restrict__ lscale,
    float* __restrict__ Gout, float* __restrict__ glsc) {
  const int g = blockIdx.x;
  const int tid = threadIdx.x;
  const int j = tid & 63;
  const int w = tid >> 6;
  __shared__ float Xa[64 * 68];
  __shared__ float Xb[64 * 68];
  __shared__ float Ma[64 * 68];
  __shared__ float Mb[64 * 68];
  __shared__ float red[4];

  // prologue: X <- M0 (transposed to [r][i]), Mcur <- M1 (linear [k][j])
  {
    const float* M0 = Mout + (size_t)(8 * g) * 4096;
    const float* M1 = Mout + (size_t)(8 * g + 1) * 4096;
    for (int idx = tid; idx < 4096; idx += 256) {
      int i = idx >> 6, r = idx & 63;
      Xa[r * 68 + i] = M0[idx];
      Ma[i * 68 + r] = M1[idx];
    }
  }
  __syncthreads();

  float lsc = 0.f;
  float* Xcur = Xa; float* Xnxt = Xb;
  float* Mcur = Ma; float* Mnxt = Mb;

  for (int m = 1; m < 8; ++m) {
    // issue next matrix's global loads first (latency hides under compute)
    float4 pf[4];
    if (m < 7) {
      const float* Mn = Mout + (size_t)(8 * g + m + 1) * 4096;
#pragma unroll
      for (int ii = 0; ii < 4; ++ii)
        pf[ii] = *(const float4*)(Mn + tid * 4 + 1024 * ii);
    }

    float acc[16];
#pragma unroll
    for (int i = 0; i < 16; ++i) acc[i] = 0.f;

#pragma unroll 4
    for (int k = 0; k < 64; ++k) {
      float mv = Mcur[k * 68 + j];                 // conflict-free (consecutive dwords)
      const float* xr = Xcur + k * 68 + (w << 4);  // wave-uniform broadcast
      float4 x0 = *(const float4*)(xr + 0);
      float4 x1 = *(const float4*)(xr + 4);
      float4 x2 = *(const float4*)(xr + 8);
      float4 x3 = *(const float4*)(xr + 12);
      acc[0]  = fmaf(mv, x0.x, acc[0]);  acc[1]  = fmaf(mv, x0.y, acc[1]);
      acc[2]  = fmaf(mv, x0.z, acc[2]);  acc[3]  = fmaf(mv, x0.w, acc[3]);
      acc[4]  = fmaf(mv, x1.x, acc[4]);  acc[5]  = fmaf(mv, x1.y, acc[5]);
      acc[6]  = fmaf(mv, x1.z, acc[6]);  acc[7]  = fmaf(mv, x1.w, acc[7]);
      acc[8]  = fmaf(mv, x2.x, acc[8]);  acc[9]  = fmaf(mv, x2.y, acc[9]);
      acc[10] = fmaf(mv, x2.z, acc[10]); acc[11] = fmaf(mv, x2.w, acc[11]);
      acc[12] = fmaf(mv, x3.x, acc[12]); acc[13] = fmaf(mv, x3.y, acc[13]);
      acc[14] = fmaf(mv, x3.z, acc[14]); acc[15] = fmaf(mv, x3.w, acc[15]);
    }

    // block-wide max (entries all > 0)
    float lm = acc[0];
#pragma unroll
    for (int i = 1; i < 16; ++i) lm = fmaxf(lm, acc[i]);
#pragma unroll
    for (int d = 1; d < 64; d <<= 1) lm = fmaxf(lm, __shfl_xor(lm, d));
    if ((tid & 63) == 0) red[w] = lm;
    __syncthreads();   // also: all reads of Xcur/Mcur done
    float bm = fmaxf(fmaxf(red[0], red[1]), fmaxf(red[2], red[3]));
    float inv = 1.f / bm;
    lsc += __logf(bm);
#pragma unroll
    for (int i = 0; i < 16; ++i)
      Xnxt[j * 68 + (w << 4) + i] = acc[i] * inv;
    if (m < 7) {
#pragma unroll
      for (int ii = 0; ii < 4; ++ii) {
        int idx = tid * 4 + 1024 * ii;
        int k = idx >> 6, jj = idx & 63;
        *(float4*)(Mnxt + k * 68 + jj) = pf[ii];
      }
    }
    __syncthreads();
    float* t = Xcur; Xcur = Xnxt; Xnxt = t;
    float* tm = Mcur; Mcur = Mnxt; Mnxt = tm;
  }

  // store G: Gout[g][i][r] = G[r][i]
  float* out = Gout + (size_t)g * 4096;
  for (int idx = tid; idx < 4096; idx += 256) {
    int i = idx >> 6, r = idx & 63;
    out[idx] = Xcur[r * 68 + i];
  }
  if (tid == 0) {
    float s = lsc;
#pragma unroll
    for (int m = 0; m < 8; ++m) s += lscale[8 * g + m];
    glsc[g] = s;
  }
}

// ---------------- level-2 combine: 16 sequential mat-vecs ----------------
__global__ __launch_bounds__(256) void final_combine(
    const float* __restrict__ Gout, const float* __restrict__ glsc,
    const float* __restrict__ peT, const float* __restrict__ ps,
    const float* __restrict__ pb, float* __restrict__ out) {
  const int tid = threadIdx.x;
  const int j = tid & 63, w = tid >> 6;
  __shared__ float vsh[64];
  __shared__ float part[4 * 64];
  if (tid < 64) vsh[tid] = ps[tid] * peT[(size_t)tid * 8192];   // f0
  __syncthreads();
  double lsc = 0.0;
  for (int gph = 0; gph < 16; ++gph) {
    const float* Gc = Gout + (size_t)gph * 4096;
    const int k0 = w << 4;
    float a0 = 0.f, a1 = 0.f, a2 = 0.f, a3 = 0.f;
#pragma unroll
    for (int kk = 0; kk < 16; kk += 4) {
      a0 = fmaf(vsh[k0 + kk + 0], Gc[(k0 + kk + 0) * 64 + j], a0);
      a1 = fmaf(vsh[k0 + kk + 1], Gc[(k0 + kk + 1) * 64 + j], a1);
      a2 = fmaf(vsh[k0 + kk + 2], Gc[(k0 + kk + 2) * 64 + j], a2);
      a3 = fmaf(vsh[k0 + kk + 3], Gc[(k0 + kk + 3) * 64 + j], a3);
    }
    part[w * 64 + j] = (a0 + a1) + (a2 + a3);
    __syncthreads();
    if (w == 0) {
      float u = part[j] + part[64 + j] + part[128 + j] + part[192 + j];
      float mx = u;
#pragma unroll
      for (int d = 1; d < 64; d <<= 1) mx = fmaxf(mx, __shfl_xor(mx, d));
      vsh[j] = u / mx;
      lsc += (double)__logf(mx) + (double)glsc[gph];
    }
    __syncthreads();
  }
  if (w == 0) {
    float z = vsh[j] * pb[T_LEN * 64 + j];
#pragma unroll
    for (int d = 1; d < 64; d <<= 1) z += __shfl_xor(z, d);
    if (j == 0) out[0] = (float)(-((double)logf(z) + lsc));
  }
}

extern "C" void kernel_launch(void* const* d_in, const int* in_sizes, int n_in,
                              void* d_out, int out_size, void* d_ws, size_t ws_size,
                              hipStream_t stream) {
  const float* s_i      = (const float*)d_in[0];
  const float* W_action = (const float*)d_in[1];
  const float* W_stop   = (const float*)d_in[2];
  const float* W_start  = (const float*)d_in[3];
  const int*   actions  = (const int*)d_in[4];

  char* ws = (char*)d_ws;
  u16*   s_bf  = (u16*)(ws + WS_SBF);
  u16*   wa_t  = (u16*)(ws + WS_WAT);
  u16*   wsm_t = (u16*)(ws + WS_WSMT);
  float* peT   = (float*)(ws + WS_PE);
  float* ps    = (float*)(ws + WS_PS);
  float* pb    = (float*)(ws + WS_PB);
  float* pc    = (float*)(ws + WS_PC);
  float* Mout  = (float*)(ws + WS_MOUT);
  float* lsc   = (float*)(ws + WS_LSC);
  float* Gout  = (float*)(ws + WS_GOUT);
  float* glsc  = (float*)(ws + WS_GLSC);

  conv_s<<<8256, 256, 0, stream>>>(s_i, s_bf);
  conv_wa<<<4096, 256, 0, stream>>>(W_action, wa_t);
  conv_wsm<<<192, 256, 0, stream>>>(W_stop, W_start, wsm_t);
  small_gemm<<<129, 256, 0, stream>>>(s_bf, wsm_t, ps, pb, pc);
  act_gemm<<<4096, 256, 0, stream>>>(s_bf, wa_t, actions, peT);
  chunk_kernel<<<128, 256, 0, stream>>>(peT, ps, pb, pc, Mout, lsc);
  group_combine<<<16, 256, 0, stream>>>(Mout, lsc, Gout, glsc);
  final_combine<<<1, 256, 0, stream>>>(Gout, glsc, peT, ps, pb, (float*)d_out);
}